// Round 1
// baseline (11358.334 us; speedup 1.0000x reference)
//
#include <hip/hip_runtime.h>
#include <hip/hip_bf16.h>

#define NN 50000
#define NE 400000
#define FH 64

__device__ __forceinline__ float silu_f(float x) {
    // x * sigmoid(x) = x / (1 + exp(-x)); v_exp + v_rcp, ~1ulp each — fine vs 0.169 threshold
    return x * __builtin_amdgcn_rcpf(1.0f + __expf(-x));
}

// src [L][K][O] row-major -> dst [L][O][Kpad]
__global__ void transpose_w(const float* __restrict__ src, float* __restrict__ dst,
                            int K, int O, int Kpad, int total) {
    int t = blockIdx.x * 256 + threadIdx.x;
    if (t >= total) return;
    int ko = K * O;
    int l = t / ko;
    int r = t - l * ko;
    int k = r / O;
    int o = r - k * O;
    dst[(l * O + o) * Kpad + k] = src[t];
}

__global__ void embed_kernel(const float* __restrict__ x, const float* __restrict__ W,
                             const float* __restrict__ b, float* __restrict__ feats) {
    int t = blockIdx.x * 256 + threadIdx.x;
    if (t >= NN * FH) return;
    int n = t >> 6, hcol = t & 63;   // n uniform per wave -> x row scalar-loaded
    float acc = b[hcol];
    #pragma unroll
    for (int k = 0; k < 8; k++) acc += x[n * 8 + k] * W[k * FH + hcol];
    feats[t] = acc;
}

__global__ __launch_bounds__(256, 2) void edge_kernel(
    const int* __restrict__ ei, const float* __restrict__ eattr,
    const float* __restrict__ feats, const float* __restrict__ coors_in,
    float* __restrict__ coors_out, float* __restrict__ m_out,
    const float* __restrict__ W1T,   // [260][132], W1T[o][k] = eW1[k][o]
    const float* __restrict__ b1,    // [260]
    const float* __restrict__ W2,    // [260][64] original layout (row o contiguous)
    const float* __restrict__ b2,    // [64]
    const float* __restrict__ cW1T,  // [256][64]
    const float* __restrict__ cb1,   // [256]
    const float* __restrict__ cW2,   // [256] (column vector, contiguous)
    const float* __restrict__ cb2)   // [1]
{
    int e = blockIdx.x * 256 + threadIdx.x;
    if (e >= NE) return;
    int row = ei[e];
    int col = ei[NE + e];

    float rx = coors_in[row * 3 + 0] - coors_in[col * 3 + 0];
    float ry = coors_in[row * 3 + 1] - coors_in[col * 3 + 1];
    float rz = coors_in[row * 3 + 2] - coors_in[col * 3 + 2];
    float dist = rx * rx + ry * ry + rz * rz;
    float eav = eattr[e];

    float fi[64], fj[64];
    {
        const float4* p = (const float4*)(feats + (size_t)row * FH);
        const float4* q = (const float4*)(feats + (size_t)col * FH);
        #pragma unroll
        for (int t = 0; t < 16; t++) {
            float4 a = p[t], b = q[t];
            fi[4 * t] = a.x; fi[4 * t + 1] = a.y; fi[4 * t + 2] = a.z; fi[4 * t + 3] = a.w;
            fj[4 * t] = b.x; fj[4 * t + 1] = b.y; fj[4 * t + 2] = b.z; fj[4 * t + 3] = b.w;
        }
    }

    float macc[64];
    #pragma unroll
    for (int j = 0; j < 64; j++) macc[j] = b2[j];

    // hidden1 unit o -> silu -> immediately scatter into macc (m = h1 @ W2)
    for (int o = 0; o < 260; o++) {
        const float* w = W1T + o * 132;   // uniform address -> s_load
        float a0 = b1[o], a1 = 0.f, a2 = 0.f, a3 = 0.f;
        #pragma unroll
        for (int k = 0; k < 64; k += 4) {
            a0 += fi[k] * w[k];
            a1 += fi[k + 1] * w[k + 1];
            a2 += fi[k + 2] * w[k + 2];
            a3 += fi[k + 3] * w[k + 3];
        }
        #pragma unroll
        for (int k = 0; k < 64; k += 4) {
            a0 += fj[k] * w[64 + k];
            a1 += fj[k + 1] * w[64 + k + 1];
            a2 += fj[k + 2] * w[64 + k + 2];
            a3 += fj[k + 3] * w[64 + k + 3];
        }
        a0 += eav * w[128];
        a1 += dist * w[129];
        float h1 = silu_f((a0 + a1) + (a2 + a3));
        const float* w2 = W2 + o * 64;
        #pragma unroll
        for (int j = 0; j < 64; j++) macc[j] += h1 * w2[j];
    }

    // m = silu(macc)  (macc already includes eb2)
    #pragma unroll
    for (int j = 0; j < 64; j++) macc[j] = silu_f(macc[j]);

    // coors_mlp: cw = silu(m @ cW1 + cb1) @ cW2 + cb2  (no silu on final)
    float cw = cb2[0];
    for (int p = 0; p < 256; p++) {
        const float* w = cW1T + p * 64;
        float a0 = cb1[p], a1 = 0.f, a2 = 0.f, a3 = 0.f;
        #pragma unroll
        for (int k = 0; k < 64; k += 4) {
            a0 += macc[k] * w[k];
            a1 += macc[k + 1] * w[k + 1];
            a2 += macc[k + 2] * w[k + 2];
            a3 += macc[k + 3] * w[k + 3];
        }
        cw += silu_f((a0 + a1) + (a2 + a3)) * cW2[p];
    }

    atomicAdd(&coors_out[row * 3 + 0], cw * rx);
    atomicAdd(&coors_out[row * 3 + 1], cw * ry);
    atomicAdd(&coors_out[row * 3 + 2], cw * rz);

    float* mi = m_out + (size_t)row * FH;
    #pragma unroll
    for (int j = 0; j < 64; j++) atomicAdd(&mi[j], macc[j]);
}

__global__ __launch_bounds__(256, 2) void node_kernel(
    float* __restrict__ feats, const float* __restrict__ m_i,
    const float* __restrict__ W1T,  // [128][128], W1T[o][k] = nW1[k][o]
    const float* __restrict__ b1,   // [128]
    const float* __restrict__ W2,   // [128][64]
    const float* __restrict__ b2)   // [64]
{
    int n = blockIdx.x * 256 + threadIdx.x;
    if (n >= NN) return;
    float h[128];
    {
        const float4* p = (const float4*)(feats + (size_t)n * FH);
        const float4* q = (const float4*)(m_i + (size_t)n * FH);
        #pragma unroll
        for (int t = 0; t < 16; t++) {
            float4 a = p[t], b = q[t];
            h[4 * t] = a.x; h[4 * t + 1] = a.y; h[4 * t + 2] = a.z; h[4 * t + 3] = a.w;
            h[64 + 4 * t] = b.x; h[64 + 4 * t + 1] = b.y; h[64 + 4 * t + 2] = b.z; h[64 + 4 * t + 3] = b.w;
        }
    }
    float outv[64];
    #pragma unroll
    for (int j = 0; j < 64; j++) outv[j] = b2[j];

    for (int o = 0; o < 128; o++) {
        const float* w = W1T + o * 128;
        float a0 = b1[o], a1 = 0.f, a2 = 0.f, a3 = 0.f;
        #pragma unroll
        for (int k = 0; k < 128; k += 4) {
            a0 += h[k] * w[k];
            a1 += h[k + 1] * w[k + 1];
            a2 += h[k + 2] * w[k + 2];
            a3 += h[k + 3] * w[k + 3];
        }
        float hv = silu_f((a0 + a1) + (a2 + a3));
        const float* w2 = W2 + o * 64;
        #pragma unroll
        for (int j = 0; j < 64; j++) outv[j] += hv * w2[j];
    }
    float* fr = feats + (size_t)n * FH;
    #pragma unroll
    for (int j = 0; j < 64; j++) fr[j] = h[j] + outv[j];
}

__global__ void final_kernel(const float* __restrict__ feats, const float* __restrict__ linW,
                             const float* __restrict__ linb, float* __restrict__ out) {
    int t = blockIdx.x * 256 + threadIdx.x;
    int n = t >> 6;
    int lane = threadIdx.x & 63;
    if (n >= NN) return;
    float v = feats[(size_t)n * FH + lane] * linW[lane];
    #pragma unroll
    for (int off = 32; off > 0; off >>= 1) v += __shfl_down(v, off);
    if (lane == 0) out[n] = v + linb[0];
}

extern "C" void kernel_launch(void* const* d_in, const int* in_sizes, int n_in,
                              void* d_out, int out_size, void* d_ws, size_t ws_size,
                              hipStream_t stream) {
    const float* x      = (const float*)d_in[0];
    const float* pos    = (const float*)d_in[1];
    const int*   ei     = (const int*)d_in[2];
    const float* eattr  = (const float*)d_in[3];
    const float* embedW = (const float*)d_in[4];
    const float* embedb = (const float*)d_in[5];
    const float* eW1    = (const float*)d_in[6];
    const float* eb1    = (const float*)d_in[7];
    const float* eW2    = (const float*)d_in[8];
    const float* eb2    = (const float*)d_in[9];
    const float* cW1    = (const float*)d_in[10];
    const float* cb1    = (const float*)d_in[11];
    const float* cW2    = (const float*)d_in[12];
    const float* cb2    = (const float*)d_in[13];
    const float* nW1    = (const float*)d_in[14];
    const float* nb1    = (const float*)d_in[15];
    const float* nW2    = (const float*)d_in[16];
    const float* nb2    = (const float*)d_in[17];
    const float* linW   = (const float*)d_in[18];
    const float* linb   = (const float*)d_in[19];
    float* out = (float*)d_out;

    float* ws = (float*)d_ws;
    float* feats = ws;  ws += (size_t)NN * FH;
    float* m_i   = ws;  ws += (size_t)NN * FH;
    float* cA    = ws;  ws += (size_t)NN * 3;
    float* cB    = ws;  ws += (size_t)NN * 3;
    float* eW1T  = ws;  ws += 3 * 260 * 132;
    float* cW1T  = ws;  ws += 3 * 256 * 64;
    float* nW1T  = ws;  ws += 3 * 128 * 128;

    // Weight transposes (columns -> contiguous rows for scalar-load access)
    transpose_w<<<(3 * 130 * 260 + 255) / 256, 256, 0, stream>>>(eW1, eW1T, 130, 260, 132, 3 * 130 * 260);
    transpose_w<<<(3 * 64 * 256 + 255) / 256, 256, 0, stream>>>(cW1, cW1T, 64, 256, 64, 3 * 64 * 256);
    transpose_w<<<(3 * 128 * 128 + 255) / 256, 256, 0, stream>>>(nW1, nW1T, 128, 128, 128, 3 * 128 * 128);

    embed_kernel<<<(NN * FH + 255) / 256, 256, 0, stream>>>(x, embedW, embedb, feats);
    hipMemcpyAsync(cA, pos, (size_t)NN * 3 * sizeof(float), hipMemcpyDeviceToDevice, stream);

    float* ccur = cA;
    float* cnext = cB;
    for (int l = 0; l < 3; l++) {
        hipMemsetAsync(m_i, 0, (size_t)NN * FH * sizeof(float), stream);
        hipMemcpyAsync(cnext, ccur, (size_t)NN * 3 * sizeof(float), hipMemcpyDeviceToDevice, stream);
        edge_kernel<<<(NE + 255) / 256, 256, 0, stream>>>(
            ei, eattr, feats, ccur, cnext, m_i,
            eW1T + l * 260 * 132, eb1 + l * 260, eW2 + l * 260 * 64, eb2 + l * 64,
            cW1T + l * 256 * 64, cb1 + l * 256, cW2 + l * 256, cb2 + l);
        node_kernel<<<(NN + 255) / 256, 256, 0, stream>>>(
            feats, m_i, nW1T + l * 128 * 128, nb1 + l * 128, nW2 + l * 128 * 64, nb2 + l * 64);
        float* tmp = ccur; ccur = cnext; cnext = tmp;
    }
    final_kernel<<<(NN * FH) / 256, 256, 0, stream>>>(feats, linW, linb, out);
}

// Round 2
// 8008.999 us; speedup vs baseline: 1.4182x; 1.4182x over previous
//
#include <hip/hip_runtime.h>
#include <hip/hip_bf16.h>

#define NN 50000
#define NE 400000
#define FH 64

__device__ __forceinline__ float silu_f(float x) {
    return x * __builtin_amdgcn_rcpf(1.0f + __expf(-x));
}

// src [L][K][O] row-major -> dst [L][O][Kpad]
__global__ void transpose_w(const float* __restrict__ src, float* __restrict__ dst,
                            int K, int O, int Kpad, int total) {
    int t = blockIdx.x * 256 + threadIdx.x;
    if (t >= total) return;
    int ko = K * O;
    int l = t / ko;
    int r = t - l * ko;
    int k = r / O;
    int o = r - k * O;
    dst[(l * O + o) * Kpad + k] = src[t];
}

__global__ void embed_kernel(const float* __restrict__ x, const float* __restrict__ W,
                             const float* __restrict__ b, float* __restrict__ feats) {
    int t = blockIdx.x * 256 + threadIdx.x;
    if (t >= NN * FH) return;
    int n = t >> 6, hcol = t & 63;
    float acc = b[hcol];
    #pragma unroll
    for (int k = 0; k < 8; k++) acc += x[n * 8 + k] * W[k * FH + hcol];
    feats[t] = acc;
}

// ---------- CSR build (once per launch; edge_index is fixed) ----------
__global__ void hist_kernel(const int* __restrict__ ei, int* __restrict__ deg) {
    int e = blockIdx.x * 256 + threadIdx.x;
    if (e >= NE) return;
    atomicAdd(&deg[ei[e]], 1);
}

__global__ void scan_kernel(const int* __restrict__ deg, int* __restrict__ off,
                            int* __restrict__ cursor) {
    __shared__ int sa[1024], sb[1024];
    int t = threadIdx.x;
    const int CH = (NN + 1023) / 1024;  // 49
    int base = t * CH;
    int s = 0;
    for (int i = 0; i < CH; i++) {
        int idx = base + i;
        if (idx < NN) s += deg[idx];
    }
    sa[t] = s;
    __syncthreads();
    int* src = sa; int* dst = sb;
    for (int d = 1; d < 1024; d <<= 1) {
        dst[t] = src[t] + ((t >= d) ? src[t - d] : 0);
        __syncthreads();
        int* tmp = src; src = dst; dst = tmp;
    }
    int run = (t == 0) ? 0 : src[t - 1];
    for (int i = 0; i < CH; i++) {
        int idx = base + i;
        if (idx < NN) { off[idx] = run; cursor[idx] = run; run += deg[idx]; }
    }
    if (t == 1023) off[NN] = src[1023];
}

__global__ void fill_kernel(const int* __restrict__ ei, int* __restrict__ cursor,
                            int* __restrict__ eidx) {
    int e = blockIdx.x * 256 + threadIdx.x;
    if (e >= NE) return;
    int p = atomicAdd(&cursor[ei[e]], 1);
    eidx[p] = e;
}

// ---------- edge MLPs: no atomics, coalesced per-edge outputs ----------
__global__ __launch_bounds__(256, 2) void edge_kernel(
    const int* __restrict__ ei, const float* __restrict__ eattr,
    const float* __restrict__ feats, const float* __restrict__ coors_in,
    __hip_bfloat16* __restrict__ m_edge,  // [E][64]
    float* __restrict__ cw_edge,          // [E]
    const float* __restrict__ W1T,   // [260][132]
    const float* __restrict__ b1,
    const float* __restrict__ W2,    // [260][64]
    const float* __restrict__ b2,
    const float* __restrict__ cW1T,  // [256][64]
    const float* __restrict__ cb1,
    const float* __restrict__ cW2,   // [256]
    const float* __restrict__ cb2)
{
    int e = blockIdx.x * 256 + threadIdx.x;
    if (e >= NE) return;
    int row = ei[e];
    int col = ei[NE + e];

    float rx = coors_in[row * 3 + 0] - coors_in[col * 3 + 0];
    float ry = coors_in[row * 3 + 1] - coors_in[col * 3 + 1];
    float rz = coors_in[row * 3 + 2] - coors_in[col * 3 + 2];
    float dist = rx * rx + ry * ry + rz * rz;
    float eav = eattr[e];

    float fi[64], fj[64];
    {
        const float4* p = (const float4*)(feats + (size_t)row * FH);
        const float4* q = (const float4*)(feats + (size_t)col * FH);
        #pragma unroll
        for (int t = 0; t < 16; t++) {
            float4 a = p[t], b = q[t];
            fi[4 * t] = a.x; fi[4 * t + 1] = a.y; fi[4 * t + 2] = a.z; fi[4 * t + 3] = a.w;
            fj[4 * t] = b.x; fj[4 * t + 1] = b.y; fj[4 * t + 2] = b.z; fj[4 * t + 3] = b.w;
        }
    }

    float macc[64];
    #pragma unroll
    for (int j = 0; j < 64; j++) macc[j] = b2[j];

    for (int o = 0; o < 260; o++) {
        const float* w = W1T + o * 132;  // wave-uniform -> scalar loads
        float a0 = b1[o], a1 = 0.f, a2 = 0.f, a3 = 0.f;
        #pragma unroll
        for (int k = 0; k < 64; k += 4) {
            a0 += fi[k] * w[k];
            a1 += fi[k + 1] * w[k + 1];
            a2 += fi[k + 2] * w[k + 2];
            a3 += fi[k + 3] * w[k + 3];
        }
        #pragma unroll
        for (int k = 0; k < 64; k += 4) {
            a0 += fj[k] * w[64 + k];
            a1 += fj[k + 1] * w[64 + k + 1];
            a2 += fj[k + 2] * w[64 + k + 2];
            a3 += fj[k + 3] * w[64 + k + 3];
        }
        a0 += eav * w[128];
        a1 += dist * w[129];
        float h1 = silu_f((a0 + a1) + (a2 + a3));
        const float* w2 = W2 + o * 64;
        #pragma unroll
        for (int j = 0; j < 64; j++) macc[j] += h1 * w2[j];
    }

    #pragma unroll
    for (int j = 0; j < 64; j++) macc[j] = silu_f(macc[j]);

    float cw = cb2[0];
    for (int p = 0; p < 256; p++) {
        const float* w = cW1T + p * 64;
        float a0 = cb1[p], a1 = 0.f, a2 = 0.f, a3 = 0.f;
        #pragma unroll
        for (int k = 0; k < 64; k += 4) {
            a0 += macc[k] * w[k];
            a1 += macc[k + 1] * w[k + 1];
            a2 += macc[k + 2] * w[k + 2];
            a3 += macc[k + 3] * w[k + 3];
        }
        cw += silu_f((a0 + a1) + (a2 + a3)) * cW2[p];
    }

    cw_edge[e] = cw;
    __hip_bfloat162* me = (__hip_bfloat162*)(m_edge + (size_t)e * FH);
    #pragma unroll
    for (int j = 0; j < 32; j++) {
        __hip_bfloat162 p2;
        p2.x = __float2bfloat16(macc[2 * j]);
        p2.y = __float2bfloat16(macc[2 * j + 1]);
        me[j] = p2;
    }
}

// ---------- wave-per-node deterministic aggregation ----------
__global__ __launch_bounds__(256) void agg_kernel(
    const int* __restrict__ off, const int* __restrict__ eidx,
    const int* __restrict__ ei, const __hip_bfloat16* __restrict__ m_edge,
    const float* __restrict__ cw_edge, const float* __restrict__ coors_in,
    float* __restrict__ coors_out, float* __restrict__ m_i)
{
    int n = blockIdx.x * 4 + (threadIdx.x >> 6);
    int j = threadIdx.x & 63;
    if (n >= NN) return;
    int s = off[n], t_end = off[n + 1];
    float pix = coors_in[n * 3 + 0], piy = coors_in[n * 3 + 1], piz = coors_in[n * 3 + 2];
    float sum = 0.f, cx = 0.f, cy = 0.f, cz = 0.f;
    for (int k = s; k < t_end; k++) {
        int e = eidx[k];
        sum += __bfloat162float(m_edge[(size_t)e * FH + j]);
        float w = cw_edge[e];         // broadcast load
        int c = ei[NE + e];           // broadcast
        cx += w * (pix - coors_in[c * 3 + 0]);
        cy += w * (piy - coors_in[c * 3 + 1]);
        cz += w * (piz - coors_in[c * 3 + 2]);
    }
    m_i[(size_t)n * FH + j] = sum;
    if (j == 0) {
        coors_out[n * 3 + 0] = pix + cx;
        coors_out[n * 3 + 1] = piy + cy;
        coors_out[n * 3 + 2] = piz + cz;
    }
}

__global__ __launch_bounds__(256, 2) void node_kernel(
    float* __restrict__ feats, const float* __restrict__ m_i,
    const float* __restrict__ W1T,  // [128][128]
    const float* __restrict__ b1,
    const float* __restrict__ W2,   // [128][64]
    const float* __restrict__ b2)
{
    int n = blockIdx.x * 256 + threadIdx.x;
    if (n >= NN) return;
    float h[128];
    {
        const float4* p = (const float4*)(feats + (size_t)n * FH);
        const float4* q = (const float4*)(m_i + (size_t)n * FH);
        #pragma unroll
        for (int t = 0; t < 16; t++) {
            float4 a = p[t], b = q[t];
            h[4 * t] = a.x; h[4 * t + 1] = a.y; h[4 * t + 2] = a.z; h[4 * t + 3] = a.w;
            h[64 + 4 * t] = b.x; h[64 + 4 * t + 1] = b.y; h[64 + 4 * t + 2] = b.z; h[64 + 4 * t + 3] = b.w;
        }
    }
    float outv[64];
    #pragma unroll
    for (int j = 0; j < 64; j++) outv[j] = b2[j];

    for (int o = 0; o < 128; o++) {
        const float* w = W1T + o * 128;
        float a0 = b1[o], a1 = 0.f, a2 = 0.f, a3 = 0.f;
        #pragma unroll
        for (int k = 0; k < 128; k += 4) {
            a0 += h[k] * w[k];
            a1 += h[k + 1] * w[k + 1];
            a2 += h[k + 2] * w[k + 2];
            a3 += h[k + 3] * w[k + 3];
        }
        float hv = silu_f((a0 + a1) + (a2 + a3));
        const float* w2 = W2 + o * 64;
        #pragma unroll
        for (int j = 0; j < 64; j++) outv[j] += hv * w2[j];
    }
    float* fr = feats + (size_t)n * FH;
    #pragma unroll
    for (int j = 0; j < 64; j++) fr[j] = h[j] + outv[j];
}

__global__ void final_kernel(const float* __restrict__ feats, const float* __restrict__ linW,
                             const float* __restrict__ linb, float* __restrict__ out) {
    int t = blockIdx.x * 256 + threadIdx.x;
    int n = t >> 6;
    int lane = threadIdx.x & 63;
    if (n >= NN) return;
    float v = feats[(size_t)n * FH + lane] * linW[lane];
    #pragma unroll
    for (int off = 32; off > 0; off >>= 1) v += __shfl_down(v, off);
    if (lane == 0) out[n] = v + linb[0];
}

extern "C" void kernel_launch(void* const* d_in, const int* in_sizes, int n_in,
                              void* d_out, int out_size, void* d_ws, size_t ws_size,
                              hipStream_t stream) {
    const float* x      = (const float*)d_in[0];
    const float* pos    = (const float*)d_in[1];
    const int*   ei     = (const int*)d_in[2];
    const float* eattr  = (const float*)d_in[3];
    const float* embedW = (const float*)d_in[4];
    const float* embedb = (const float*)d_in[5];
    const float* eW1    = (const float*)d_in[6];
    const float* eb1    = (const float*)d_in[7];
    const float* eW2    = (const float*)d_in[8];
    const float* eb2    = (const float*)d_in[9];
    const float* cW1    = (const float*)d_in[10];
    const float* cb1    = (const float*)d_in[11];
    const float* cW2    = (const float*)d_in[12];
    const float* cb2    = (const float*)d_in[13];
    const float* nW1    = (const float*)d_in[14];
    const float* nb1    = (const float*)d_in[15];
    const float* nW2    = (const float*)d_in[16];
    const float* nb2    = (const float*)d_in[17];
    const float* linW   = (const float*)d_in[18];
    const float* linb   = (const float*)d_in[19];
    float* out = (float*)d_out;

    char* wp = (char*)d_ws;
    auto alloc = [&](size_t bytes) { void* p = wp; wp += (bytes + 255) & ~(size_t)255; return p; };

    float* feats  = (float*)alloc((size_t)NN * FH * 4);
    float* m_i    = (float*)alloc((size_t)NN * FH * 4);
    float* cA     = (float*)alloc((size_t)NN * 3 * 4);
    float* cB     = (float*)alloc((size_t)NN * 3 * 4);
    float* eW1T   = (float*)alloc((size_t)3 * 260 * 132 * 4);
    float* cW1T   = (float*)alloc((size_t)3 * 256 * 64 * 4);
    float* nW1T   = (float*)alloc((size_t)3 * 128 * 128 * 4);
    int*   deg    = (int*)alloc((size_t)NN * 4);
    int*   off    = (int*)alloc((size_t)(NN + 1) * 4);
    int*   cursor = (int*)alloc((size_t)NN * 4);
    int*   eidx   = (int*)alloc((size_t)NE * 4);
    __hip_bfloat16* m_edge = (__hip_bfloat16*)alloc((size_t)NE * FH * 2);
    float* cw_e   = (float*)alloc((size_t)NE * 4);

    // Weight transposes
    transpose_w<<<(3 * 130 * 260 + 255) / 256, 256, 0, stream>>>(eW1, eW1T, 130, 260, 132, 3 * 130 * 260);
    transpose_w<<<(3 * 64 * 256 + 255) / 256, 256, 0, stream>>>(cW1, cW1T, 64, 256, 64, 3 * 64 * 256);
    transpose_w<<<(3 * 128 * 128 + 255) / 256, 256, 0, stream>>>(nW1, nW1T, 128, 128, 128, 3 * 128 * 128);

    // CSR build (edge_index is constant across layers)
    hipMemsetAsync(deg, 0, (size_t)NN * 4, stream);
    hist_kernel<<<(NE + 255) / 256, 256, 0, stream>>>(ei, deg);
    scan_kernel<<<1, 1024, 0, stream>>>(deg, off, cursor);
    fill_kernel<<<(NE + 255) / 256, 256, 0, stream>>>(ei, cursor, eidx);

    embed_kernel<<<(NN * FH + 255) / 256, 256, 0, stream>>>(x, embedW, embedb, feats);
    hipMemcpyAsync(cA, pos, (size_t)NN * 3 * 4, hipMemcpyDeviceToDevice, stream);

    float* ccur = cA;
    float* cnext = cB;
    for (int l = 0; l < 3; l++) {
        edge_kernel<<<(NE + 255) / 256, 256, 0, stream>>>(
            ei, eattr, feats, ccur, m_edge, cw_e,
            eW1T + l * 260 * 132, eb1 + l * 260, eW2 + l * 260 * 64, eb2 + l * 64,
            cW1T + l * 256 * 64, cb1 + l * 256, cW2 + l * 256, cb2 + l);
        agg_kernel<<<(NN + 3) / 4, 256, 0, stream>>>(
            off, eidx, ei, m_edge, cw_e, ccur, cnext, m_i);
        node_kernel<<<(NN + 255) / 256, 256, 0, stream>>>(
            feats, m_i, nW1T + l * 128 * 128, nb1 + l * 128, nW2 + l * 128 * 64, nb2 + l * 64);
        float* tmp = ccur; ccur = cnext; cnext = tmp;
    }
    final_kernel<<<(NN * FH) / 256, 256, 0, stream>>>(feats, linW, linb, out);
}

// Round 4
// 2275.501 us; speedup vs baseline: 4.9916x; 3.5197x over previous
//
#include <hip/hip_runtime.h>
#include <hip/hip_bf16.h>

#define NN 50000
#define NE 400000
#define FH 64

typedef __attribute__((ext_vector_type(8))) short short8;
typedef __attribute__((ext_vector_type(4))) float float4v;

__device__ __forceinline__ float silu_f(float x) {
    return x * __builtin_amdgcn_rcpf(1.0f + __expf(-x));
}
__device__ __forceinline__ short f2bf(float f) {
    __hip_bfloat16 h = __float2bfloat16(f);
    return *(short*)&h;
}
__device__ __forceinline__ float bf2f(short s) {
    __hip_bfloat16 h = *(__hip_bfloat16*)&s;
    return __bfloat162float(h);
}

// ---------------- weight prep ----------------
// src float [K][N] -> hi/lo bf16 frag pairs. tile(nt,kt) at (nt*KT+kt)*512,
// element (lane,j) = W[kt*32 + (lane>>4)*8 + j][nt*16 + (lane&15)], zero-padded.
// if k==dup, source row dup-1 is used (dist hi/lo column duplication).
__global__ void frag_prep2(const float* __restrict__ src, short* __restrict__ hi,
                           short* __restrict__ lo, int K, int N, int KT, int dup, int total) {
    int t = blockIdx.x * 256 + threadIdx.x;
    if (t >= total) return;
    int j = t & 7, lane = (t >> 3) & 63, frag = t >> 9;
    int nt = frag / KT, kt = frag - nt * KT;
    int k = kt * 32 + ((lane >> 4) << 3) + j;
    int n = nt * 16 + (lane & 15);
    if (k == dup) k = dup - 1;
    float v = (k < K && n < N) ? src[k * N + n] : 0.f;
    short h = f2bf(v);
    hi[t] = h;
    lo[t] = f2bf(v - bf2f(h));
}

__global__ void pad_b1(const float* __restrict__ src, float* __restrict__ dst) {
    int t = blockIdx.x * 256 + threadIdx.x;
    if (t >= 3 * 272) return;
    int l = t / 272, c = t - l * 272;
    dst[t] = (c < 260) ? src[l * 260 + c] : 0.f;
}

// src [L][K][O] -> dst [L][O][Kpad]  (node weights, VALU path)
__global__ void transpose_w(const float* __restrict__ src, float* __restrict__ dst,
                            int K, int O, int Kpad, int total) {
    int t = blockIdx.x * 256 + threadIdx.x;
    if (t >= total) return;
    int ko = K * O;
    int l = t / ko;
    int r = t - l * ko;
    int k = r / O;
    int o = r - k * O;
    dst[(l * O + o) * Kpad + k] = src[t];
}

__global__ void embed_kernel(const float* __restrict__ x, const float* __restrict__ W,
                             const float* __restrict__ b, float* __restrict__ feats) {
    int t = blockIdx.x * 256 + threadIdx.x;
    if (t >= NN * FH) return;
    int n = t >> 6, hcol = t & 63;
    float acc = b[hcol];
    #pragma unroll
    for (int k = 0; k < 8; k++) acc += x[n * 8 + k] * W[k * FH + hcol];
    feats[t] = acc;
}

// ---------------- CSR build ----------------
__global__ void hist_kernel(const int* __restrict__ ei, int* __restrict__ deg) {
    int e = blockIdx.x * 256 + threadIdx.x;
    if (e >= NE) return;
    atomicAdd(&deg[ei[e]], 1);
}

__global__ void scan_kernel(const int* __restrict__ deg, int* __restrict__ off,
                            int* __restrict__ cursor) {
    __shared__ int sa[1024], sb[1024];
    int t = threadIdx.x;
    const int CH = (NN + 1023) / 1024;
    int base = t * CH;
    int s = 0;
    for (int i = 0; i < CH; i++) {
        int idx = base + i;
        if (idx < NN) s += deg[idx];
    }
    sa[t] = s;
    __syncthreads();
    int* src = sa; int* dst = sb;
    for (int d = 1; d < 1024; d <<= 1) {
        dst[t] = src[t] + ((t >= d) ? src[t - d] : 0);
        __syncthreads();
        int* tmp = src; src = dst; dst = tmp;
    }
    int run = (t == 0) ? 0 : src[t - 1];
    for (int i = 0; i < CH; i++) {
        int idx = base + i;
        if (idx < NN) { off[idx] = run; cursor[idx] = run; run += deg[idx]; }
    }
    if (t == 1023) off[NN] = src[1023];
}

__global__ void fill_kernel(const int* __restrict__ ei, int* __restrict__ cursor,
                            int* __restrict__ eidx) {
    int e = blockIdx.x * 256 + threadIdx.x;
    if (e >= NE) return;
    int p = atomicAdd(&cursor[ei[e]], 1);
    eidx[p] = e;
}

// ---------------- fused MFMA edge pipeline ----------------
#define SE_STRIDE 168
#define H1_STRIDE 296
#define M_STRIDE  72

__global__ __launch_bounds__(256, 2) void edge_fused(
    const int* __restrict__ ei, const float* __restrict__ eattr,
    const float* __restrict__ feats, const float* __restrict__ coors,
    const short* __restrict__ W1h, const short* __restrict__ W1l, const float* __restrict__ b1p,
    const short* __restrict__ W2h, const short* __restrict__ W2l, const float* __restrict__ b2,
    const short* __restrict__ cW1h, const short* __restrict__ cW1l, const float* __restrict__ cb1,
    const float* __restrict__ cW2, const float* __restrict__ cb2,
    __hip_bfloat16* __restrict__ m_edge, float* __restrict__ cw_edge)
{
    __shared__ short sH1[64 * H1_STRIDE];  // 37888 B
    __shared__ short sE[64 * SE_STRIDE];   // 21504 B; reused as m tile
    short* sM = sE;

    int t = threadIdx.x;
    int e0 = blockIdx.x * 64;
    int lane = t & 63, wid = t >> 6, quad = lane >> 4, lc = lane & 15;
    int m0 = wid * 16;

    // ---- gather e_in tile: [fi(64) | fj(64) | eattr | dist_hi | dist_lo | 0...] ----
    {
        int el = t >> 2, sub = t & 3, e = e0 + el;
        int rI = ei[e], cI = ei[NE + e];
        const float4* fr = (const float4*)(feats + (size_t)rI * FH);
        const float4* fc = (const float4*)(feats + (size_t)cI * FH);
        short* er = sE + el * SE_STRIDE;
        #pragma unroll
        for (int i = 0; i < 4; i++) {
            float4 a = fr[sub * 4 + i];
            float4 b = fc[sub * 4 + i];
            int o = sub * 16 + i * 4;
            er[o + 0] = f2bf(a.x); er[o + 1] = f2bf(a.y); er[o + 2] = f2bf(a.z); er[o + 3] = f2bf(a.w);
            er[64 + o + 0] = f2bf(b.x); er[64 + o + 1] = f2bf(b.y); er[64 + o + 2] = f2bf(b.z); er[64 + o + 3] = f2bf(b.w);
        }
        #pragma unroll
        for (int i = 0; i < 10; i++) er[128 + sub * 10 + i] = 0;
        if (sub == 0) {
            float rx = coors[rI * 3 + 0] - coors[cI * 3 + 0];
            float ry = coors[rI * 3 + 1] - coors[cI * 3 + 1];
            float rz = coors[rI * 3 + 2] - coors[cI * 3 + 2];
            float dist = rx * rx + ry * ry + rz * rz;
            short dh = f2bf(dist);
            er[128] = f2bf(eattr[e]);
            er[129] = dh;
            er[130] = f2bf(dist - bf2f(dh));   // exact-ish dist via hi+lo columns
        }
        // zero H1 pad cols [272,288)
        int row = t >> 2, c0 = 272 + (t & 3) * 4;
        #pragma unroll
        for (int i = 0; i < 4; i++) sH1[row * H1_STRIDE + c0 + i] = 0;
    }
    __syncthreads();

    // ---- GEMM1: e_in[64x160] @ (W1h+W1l)[160x272] -> silu -> H1 ----
    {
        short8 af[5];
        #pragma unroll
        for (int kt = 0; kt < 5; kt++)
            af[kt] = *(const short8*)(sE + (m0 + lc) * SE_STRIDE + kt * 32 + quad * 8);
        for (int nt = 0; nt < 17; nt++) {
            int col = nt * 16 + lc;
            float bias = b1p[col];
            float4v acc = {bias, bias, bias, bias};
            #pragma unroll
            for (int kt = 0; kt < 5; kt++) {
                short8 bh = ((const short8*)(W1h + (size_t)(nt * 5 + kt) * 512))[lane];
                short8 bl = ((const short8*)(W1l + (size_t)(nt * 5 + kt) * 512))[lane];
                acc = __builtin_amdgcn_mfma_f32_16x16x32_bf16(af[kt], bh, acc, 0, 0, 0);
                acc = __builtin_amdgcn_mfma_f32_16x16x32_bf16(af[kt], bl, acc, 0, 0, 0);
            }
            #pragma unroll
            for (int r = 0; r < 4; r++)
                sH1[(m0 + quad * 4 + r) * H1_STRIDE + col] = f2bf(silu_f(acc[r]));
        }
    }
    __syncthreads();

    // ---- GEMM2: H1[64x288] @ (W2h+W2l)[288x64] -> silu -> m ----
    {
        short8 af[9];
        #pragma unroll
        for (int kt = 0; kt < 9; kt++)
            af[kt] = *(const short8*)(sH1 + (m0 + lc) * H1_STRIDE + kt * 32 + quad * 8);
        #pragma unroll
        for (int nt = 0; nt < 4; nt++) {
            int col = nt * 16 + lc;
            float bias = b2[col];
            float4v acc = {bias, bias, bias, bias};
            #pragma unroll
            for (int kt = 0; kt < 9; kt++) {
                short8 bh = ((const short8*)(W2h + (size_t)(nt * 9 + kt) * 512))[lane];
                short8 bl = ((const short8*)(W2l + (size_t)(nt * 9 + kt) * 512))[lane];
                acc = __builtin_amdgcn_mfma_f32_16x16x32_bf16(af[kt], bh, acc, 0, 0, 0);
                acc = __builtin_amdgcn_mfma_f32_16x16x32_bf16(af[kt], bl, acc, 0, 0, 0);
            }
            #pragma unroll
            for (int r = 0; r < 4; r++)
                sM[(m0 + quad * 4 + r) * M_STRIDE + col] = f2bf(silu_f(acc[r]));
        }
    }
    __syncthreads();

    // ---- copy m tile to global (coalesced 16B stores) ----
    {
        int row = t >> 2, c0 = (t & 3) * 16;
        short8 v0 = *(const short8*)(sM + row * M_STRIDE + c0);
        short8 v1 = *(const short8*)(sM + row * M_STRIDE + c0 + 8);
        short* mg = (short*)m_edge + (size_t)(e0 + row) * FH + c0;
        *(short8*)(mg) = v0;
        *(short8*)(mg + 8) = v1;
    }

    // ---- GEMM3 + dot: cw = silu(m@cW1+cb1) @ cW2 + cb2 ----
    {
        short8 af[2];
        #pragma unroll
        for (int kt = 0; kt < 2; kt++)
            af[kt] = *(const short8*)(sM + (m0 + lc) * M_STRIDE + kt * 32 + quad * 8);
        float cwacc[4] = {0.f, 0.f, 0.f, 0.f};
        for (int nt = 0; nt < 16; nt++) {
            int col = nt * 16 + lc;
            float bias = cb1[col];
            float4v acc = {bias, bias, bias, bias};
            #pragma unroll
            for (int kt = 0; kt < 2; kt++) {
                short8 bh = ((const short8*)(cW1h + (size_t)(nt * 2 + kt) * 512))[lane];
                short8 bl = ((const short8*)(cW1l + (size_t)(nt * 2 + kt) * 512))[lane];
                acc = __builtin_amdgcn_mfma_f32_16x16x32_bf16(af[kt], bh, acc, 0, 0, 0);
                acc = __builtin_amdgcn_mfma_f32_16x16x32_bf16(af[kt], bl, acc, 0, 0, 0);
            }
            float wv = cW2[col];
            #pragma unroll
            for (int r = 0; r < 4; r++) {
                float p = silu_f(acc[r]) * wv;
                p += __shfl_xor(p, 1);
                p += __shfl_xor(p, 2);
                p += __shfl_xor(p, 4);
                p += __shfl_xor(p, 8);
                cwacc[r] += p;
            }
        }
        if (lc == 0) {
            float cb = cb2[0];
            #pragma unroll
            for (int r = 0; r < 4; r++)
                cw_edge[e0 + m0 + quad * 4 + r] = cwacc[r] + cb;
        }
    }
}

// ---------------- wave-per-node aggregation ----------------
__global__ __launch_bounds__(256) void agg_kernel(
    const int* __restrict__ off, const int* __restrict__ eidx,
    const int* __restrict__ ei, const __hip_bfloat16* __restrict__ m_edge,
    const float* __restrict__ cw_edge, const float* __restrict__ coors_in,
    float* __restrict__ coors_out, float* __restrict__ m_i)
{
    int n = blockIdx.x * 4 + (threadIdx.x >> 6);
    int j = threadIdx.x & 63;
    if (n >= NN) return;
    int s = off[n], t_end = off[n + 1];
    float pix = coors_in[n * 3 + 0], piy = coors_in[n * 3 + 1], piz = coors_in[n * 3 + 2];
    float sum = 0.f, cx = 0.f, cy = 0.f, cz = 0.f;
    for (int k = s; k < t_end; k++) {
        int e = eidx[k];
        sum += __bfloat162float(m_edge[(size_t)e * FH + j]);
        float w = cw_edge[e];
        int c = ei[NE + e];
        cx += w * (pix - coors_in[c * 3 + 0]);
        cy += w * (piy - coors_in[c * 3 + 1]);
        cz += w * (piz - coors_in[c * 3 + 2]);
    }
    m_i[(size_t)n * FH + j] = sum;
    if (j == 0) {
        coors_out[n * 3 + 0] = pix + cx;
        coors_out[n * 3 + 1] = piy + cy;
        coors_out[n * 3 + 2] = piz + cz;
    }
}

__global__ __launch_bounds__(256, 2) void node_kernel(
    float* __restrict__ feats, const float* __restrict__ m_i,
    const float* __restrict__ W1T, const float* __restrict__ b1,
    const float* __restrict__ W2, const float* __restrict__ b2)
{
    int n = blockIdx.x * 256 + threadIdx.x;
    if (n >= NN) return;
    float h[128];
    {
        const float4* p = (const float4*)(feats + (size_t)n * FH);
        const float4* q = (const float4*)(m_i + (size_t)n * FH);
        #pragma unroll
        for (int t = 0; t < 16; t++) {
            float4 a = p[t], b = q[t];
            h[4 * t] = a.x; h[4 * t + 1] = a.y; h[4 * t + 2] = a.z; h[4 * t + 3] = a.w;
            h[64 + 4 * t] = b.x; h[64 + 4 * t + 1] = b.y; h[64 + 4 * t + 2] = b.z; h[64 + 4 * t + 3] = b.w;
        }
    }
    float outv[64];
    #pragma unroll
    for (int j = 0; j < 64; j++) outv[j] = b2[j];

    for (int o = 0; o < 128; o++) {
        const float* w = W1T + o * 128;
        float a0 = b1[o], a1 = 0.f, a2 = 0.f, a3 = 0.f;
        #pragma unroll
        for (int k = 0; k < 128; k += 4) {
            a0 += h[k] * w[k];
            a1 += h[k + 1] * w[k + 1];
            a2 += h[k + 2] * w[k + 2];
            a3 += h[k + 3] * w[k + 3];
        }
        float hv = silu_f((a0 + a1) + (a2 + a3));
        const float* w2 = W2 + o * 64;
        #pragma unroll
        for (int j = 0; j < 64; j++) outv[j] += hv * w2[j];
    }
    float* fr = feats + (size_t)n * FH;
    #pragma unroll
    for (int j = 0; j < 64; j++) fr[j] = h[j] + outv[j];
}

__global__ void final_kernel(const float* __restrict__ feats, const float* __restrict__ linW,
                             const float* __restrict__ linb, float* __restrict__ out) {
    int t = blockIdx.x * 256 + threadIdx.x;
    int n = t >> 6;
    int lane = threadIdx.x & 63;
    if (n >= NN) return;
    float v = feats[(size_t)n * FH + lane] * linW[lane];
    #pragma unroll
    for (int off = 32; off > 0; off >>= 1) v += __shfl_down(v, off);
    if (lane == 0) out[n] = v + linb[0];
}

extern "C" void kernel_launch(void* const* d_in, const int* in_sizes, int n_in,
                              void* d_out, int out_size, void* d_ws, size_t ws_size,
                              hipStream_t stream) {
    const float* x      = (const float*)d_in[0];
    const float* pos    = (const float*)d_in[1];
    const int*   ei     = (const int*)d_in[2];
    const float* eattr  = (const float*)d_in[3];
    const float* embedW = (const float*)d_in[4];
    const float* embedb = (const float*)d_in[5];
    const float* eW1    = (const float*)d_in[6];
    const float* eb1    = (const float*)d_in[7];
    const float* eW2    = (const float*)d_in[8];
    const float* eb2    = (const float*)d_in[9];
    const float* cW1    = (const float*)d_in[10];
    const float* cb1    = (const float*)d_in[11];
    const float* cW2    = (const float*)d_in[12];
    const float* cb2    = (const float*)d_in[13];
    const float* nW1    = (const float*)d_in[14];
    const float* nb1    = (const float*)d_in[15];
    const float* nW2    = (const float*)d_in[16];
    const float* nb2    = (const float*)d_in[17];
    const float* linW   = (const float*)d_in[18];
    const float* linb   = (const float*)d_in[19];
    float* out = (float*)d_out;

    char* wp = (char*)d_ws;
    auto alloc = [&](size_t bytes) { void* p = wp; wp += (bytes + 255) & ~(size_t)255; return p; };

    const int W1F_L = 17 * 5 * 512;
    const int W2F_L = 4 * 9 * 512;
    const int CW1F_L = 16 * 2 * 512;

    float* feats  = (float*)alloc((size_t)NN * FH * 4);
    float* m_i    = (float*)alloc((size_t)NN * FH * 4);
    float* cA     = (float*)alloc((size_t)NN * 3 * 4);
    float* cB     = (float*)alloc((size_t)NN * 3 * 4);
    short* W1fh   = (short*)alloc((size_t)3 * W1F_L * 2);
    short* W1fl   = (short*)alloc((size_t)3 * W1F_L * 2);
    short* W2fh   = (short*)alloc((size_t)3 * W2F_L * 2);
    short* W2fl   = (short*)alloc((size_t)3 * W2F_L * 2);
    short* cW1fh  = (short*)alloc((size_t)3 * CW1F_L * 2);
    short* cW1fl  = (short*)alloc((size_t)3 * CW1F_L * 2);
    float* b1p    = (float*)alloc((size_t)3 * 272 * 4);
    float* nW1T   = (float*)alloc((size_t)3 * 128 * 128 * 4);
    int*   deg    = (int*)alloc((size_t)NN * 4);
    int*   off    = (int*)alloc((size_t)(NN + 1) * 4);
    int*   cursor = (int*)alloc((size_t)NN * 4);
    int*   eidx   = (int*)alloc((size_t)NE * 4);
    __hip_bfloat16* m_edge = (__hip_bfloat16*)alloc((size_t)NE * FH * 2);
    float* cw_e   = (float*)alloc((size_t)NE * 4);

    // weight prep: hi/lo bf16 split; W1 gets dist duplicated into row 130
    for (int l = 0; l < 3; l++) {
        frag_prep2<<<(W1F_L + 255) / 256, 256, 0, stream>>>(
            eW1 + (size_t)l * 130 * 260, W1fh + (size_t)l * W1F_L, W1fl + (size_t)l * W1F_L,
            131, 260, 5, 130, W1F_L);
        frag_prep2<<<(W2F_L + 255) / 256, 256, 0, stream>>>(
            eW2 + (size_t)l * 260 * 64, W2fh + (size_t)l * W2F_L, W2fl + (size_t)l * W2F_L,
            260, 64, 9, -1, W2F_L);
        frag_prep2<<<(CW1F_L + 255) / 256, 256, 0, stream>>>(
            cW1 + (size_t)l * 64 * 256, cW1fh + (size_t)l * CW1F_L, cW1fl + (size_t)l * CW1F_L,
            64, 256, 2, -1, CW1F_L);
    }
    pad_b1<<<(3 * 272 + 255) / 256, 256, 0, stream>>>(eb1, b1p);
    transpose_w<<<(3 * 128 * 128 + 255) / 256, 256, 0, stream>>>(nW1, nW1T, 128, 128, 128, 3 * 128 * 128);

    // CSR build
    hipMemsetAsync(deg, 0, (size_t)NN * 4, stream);
    hist_kernel<<<(NE + 255) / 256, 256, 0, stream>>>(ei, deg);
    scan_kernel<<<1, 1024, 0, stream>>>(deg, off, cursor);
    fill_kernel<<<(NE + 255) / 256, 256, 0, stream>>>(ei, cursor, eidx);

    embed_kernel<<<(NN * FH + 255) / 256, 256, 0, stream>>>(x, embedW, embedb, feats);
    hipMemcpyAsync(cA, pos, (size_t)NN * 3 * 4, hipMemcpyDeviceToDevice, stream);

    float* ccur = cA;
    float* cnext = cB;
    for (int l = 0; l < 3; l++) {
        edge_fused<<<NE / 64, 256, 0, stream>>>(
            ei, eattr, feats, ccur,
            W1fh + (size_t)l * W1F_L, W1fl + (size_t)l * W1F_L, b1p + l * 272,
            W2fh + (size_t)l * W2F_L, W2fl + (size_t)l * W2F_L, eb2 + l * 64,
            cW1fh + (size_t)l * CW1F_L, cW1fl + (size_t)l * CW1F_L, cb1 + l * 256,
            cW2 + l * 256, cb2 + l,
            m_edge, cw_e);
        agg_kernel<<<(NN + 3) / 4, 256, 0, stream>>>(
            off, eidx, ei, m_edge, cw_e, ccur, cnext, m_i);
        node_kernel<<<(NN + 255) / 256, 256, 0, stream>>>(
            feats, m_i, nW1T + l * 128 * 128, nb1 + l * 128, nW2 + l * 128 * 64, nb2 + l * 64);
        float* tmp = ccur; ccur = cnext; cnext = tmp;
    }
    final_kernel<<<(NN * FH) / 256, 256, 0, stream>>>(feats, linW, linb, out);
}

// Round 5
// 1058.418 us; speedup vs baseline: 10.7314x; 2.1499x over previous
//
#include <hip/hip_runtime.h>
#include <hip/hip_bf16.h>

#define NN 50000
#define NNP 50048   // padded to 64-node blocks
#define NE 400000
#define FH 64

typedef __attribute__((ext_vector_type(8))) short short8;
typedef __attribute__((ext_vector_type(4))) float float4v;

__device__ __forceinline__ float silu_f(float x) {
    return x * __builtin_amdgcn_rcpf(1.0f + __expf(-x));
}
__device__ __forceinline__ short f2bf(float f) {
    __hip_bfloat16 h = __float2bfloat16(f);
    return *(short*)&h;
}
__device__ __forceinline__ float bf2f(short s) {
    __hip_bfloat16 h = *(__hip_bfloat16*)&s;
    return __bfloat162float(h);
}

// ---------------- weight prep (all layers in one launch) ----------------
// src float [L][K][N] -> hi/lo bf16 frag pairs. frag(nt,kt) at (nt*KT+kt)*512,
// element (lane,j) = W[kt*32+(lane>>4)*8+j][nt*16+(lane&15)], zero-padded.
// if k==dup, source row dup-1 is used (dist hi/lo column duplication).
__global__ void frag_prep2(const float* __restrict__ src, short* __restrict__ hi,
                           short* __restrict__ lo, int K, int N, int KT, int dup,
                           int perL, int srcL, int total) {
    int t = blockIdx.x * 256 + threadIdx.x;
    if (t >= total) return;
    int l = t / perL, tt = t - l * perL;
    int j = tt & 7, lane = (tt >> 3) & 63, frag = tt >> 9;
    int nt = frag / KT, kt = frag - nt * KT;
    int k = kt * 32 + ((lane >> 4) << 3) + j;
    int n = nt * 16 + (lane & 15);
    if (k == dup) k = dup - 1;
    float v = (k < K && n < N) ? src[(size_t)l * srcL + k * N + n] : 0.f;
    short h = f2bf(v);
    hi[t] = h;
    lo[t] = f2bf(v - bf2f(h));
}

__global__ void pad_b1(const float* __restrict__ src, float* __restrict__ dst) {
    int t = blockIdx.x * 256 + threadIdx.x;
    if (t >= 3 * 272) return;
    int l = t / 272, c = t - l * 272;
    dst[t] = (c < 260) ? src[l * 260 + c] : 0.f;
}

__global__ void embed_kernel(const float* __restrict__ x, const float* __restrict__ W,
                             const float* __restrict__ b, float* __restrict__ feats) {
    int t = blockIdx.x * 256 + threadIdx.x;
    if (t >= NN * FH) return;
    int n = t >> 6, hcol = t & 63;
    float acc = b[hcol];
    #pragma unroll
    for (int k = 0; k < 8; k++) acc += x[n * 8 + k] * W[k * FH + hcol];
    feats[t] = acc;
}

// ---------------- CSR build ----------------
__global__ void hist_kernel(const int* __restrict__ ei, int* __restrict__ deg) {
    int e = blockIdx.x * 256 + threadIdx.x;
    if (e >= NE) return;
    atomicAdd(&deg[ei[e]], 1);
}

__global__ void scan_kernel(const int* __restrict__ deg, int* __restrict__ off,
                            int* __restrict__ cursor) {
    __shared__ int sa[1024], sb[1024];
    int t = threadIdx.x;
    const int CH = (NN + 1023) / 1024;
    int base = t * CH;
    int s = 0;
    for (int i = 0; i < CH; i++) {
        int idx = base + i;
        if (idx < NN) s += deg[idx];
    }
    sa[t] = s;
    __syncthreads();
    int* src = sa; int* dst = sb;
    for (int d = 1; d < 1024; d <<= 1) {
        dst[t] = src[t] + ((t >= d) ? src[t - d] : 0);
        __syncthreads();
        int* tmp = src; src = dst; dst = tmp;
    }
    int run = (t == 0) ? 0 : src[t - 1];
    for (int i = 0; i < CH; i++) {
        int idx = base + i;
        if (idx < NN) { off[idx] = run; cursor[idx] = run; run += deg[idx]; }
    }
    if (t == 1023) off[NN] = src[1023];
}

// emits edge data permuted into CSR order: erow/ecol/eattrp[slot]
__global__ void fill_kernel(const int* __restrict__ ei, const float* __restrict__ eattr,
                            int* __restrict__ cursor, int* __restrict__ erow,
                            int* __restrict__ ecol, float* __restrict__ eattrp) {
    int e = blockIdx.x * 256 + threadIdx.x;
    if (e >= NE) return;
    int r = ei[e];
    int p = atomicAdd(&cursor[r], 1);
    erow[p] = r;
    ecol[p] = ei[NE + e];
    eattrp[p] = eattr[e];
}

// ---------------- fused MFMA edge pipeline (N-split waves, CSR order) ----------------
#define SE_STRIDE 168
#define H1_STRIDE 296
#define M_STRIDE  72

__global__ __launch_bounds__(256, 2) void edge_fused(
    const int* __restrict__ erow, const int* __restrict__ ecol,
    const float* __restrict__ eattrp,
    const float* __restrict__ feats, const float* __restrict__ coors,
    const short* __restrict__ W1h, const short* __restrict__ W1l, const float* __restrict__ b1p,
    const short* __restrict__ W2h, const short* __restrict__ W2l, const float* __restrict__ b2,
    const short* __restrict__ cW1h, const short* __restrict__ cW1l, const float* __restrict__ cb1,
    const float* __restrict__ cW2, const float* __restrict__ cb2,
    __hip_bfloat16* __restrict__ m_edge, float* __restrict__ cwrel)
{
    __shared__ short sH1[64 * H1_STRIDE];   // 37888 B
    __shared__ short sE[64 * SE_STRIDE];    // 21504 B; sM overlays after GEMM1
    __shared__ float sRel[64 * 3];          // 768 B
    __shared__ float cwbuf[4 * 64];         // 1024 B
    short* sM = sE;

    int t = threadIdx.x;
    int k0 = blockIdx.x * 64;
    int lane = t & 63, wid = t >> 6, quad = lane >> 4, lc = lane & 15;

    // ---- gather e_in tile (CSR order): [fi | fj | eattr | dist_hi | dist_lo | 0..] ----
    {
        int el = t >> 2, sub = t & 3, k = k0 + el;
        int rI = erow[k], cI = ecol[k];
        const float4* fr = (const float4*)(feats + (size_t)rI * FH);
        const float4* fc = (const float4*)(feats + (size_t)cI * FH);
        short* er = sE + el * SE_STRIDE;
        #pragma unroll
        for (int i = 0; i < 4; i++) {
            float4 a = fr[sub * 4 + i];
            float4 b = fc[sub * 4 + i];
            int o = sub * 16 + i * 4;
            er[o + 0] = f2bf(a.x); er[o + 1] = f2bf(a.y); er[o + 2] = f2bf(a.z); er[o + 3] = f2bf(a.w);
            er[64 + o + 0] = f2bf(b.x); er[64 + o + 1] = f2bf(b.y); er[64 + o + 2] = f2bf(b.z); er[64 + o + 3] = f2bf(b.w);
        }
        #pragma unroll
        for (int i = 0; i < 10; i++) er[128 + sub * 10 + i] = 0;
        if (sub == 0) {
            float rx = coors[rI * 3 + 0] - coors[cI * 3 + 0];
            float ry = coors[rI * 3 + 1] - coors[cI * 3 + 1];
            float rz = coors[rI * 3 + 2] - coors[cI * 3 + 2];
            float dist = rx * rx + ry * ry + rz * rz;
            short dh = f2bf(dist);
            er[128] = f2bf(eattrp[k]);
            er[129] = dh;
            er[130] = f2bf(dist - bf2f(dh));
            sRel[el * 3 + 0] = rx; sRel[el * 3 + 1] = ry; sRel[el * 3 + 2] = rz;
        }
        // zero H1 pad cols [272,288)
        int row = t >> 2, c0 = 272 + (t & 3) * 4;
        #pragma unroll
        for (int i = 0; i < 4; i++) sH1[row * H1_STRIDE + c0 + i] = 0;
    }
    __syncthreads();

    // ---- GEMM1: e_in[64x160] @ W1[160x272] -> silu -> H1.  Waves split N. ----
    {
        short8 af[4][5];   // A resident: all 4 M-tiles
        #pragma unroll
        for (int m = 0; m < 4; m++)
            #pragma unroll
            for (int kt = 0; kt < 5; kt++)
                af[m][kt] = *(const short8*)(sE + (m * 16 + lc) * SE_STRIDE + kt * 32 + quad * 8);
        for (int nt = wid; nt < 17; nt += 4) {
            float bias = b1p[nt * 16 + lc];
            float4v acc[4];
            #pragma unroll
            for (int m = 0; m < 4; m++) acc[m] = (float4v){bias, bias, bias, bias};
            #pragma unroll
            for (int kt = 0; kt < 5; kt++) {
                short8 bh = ((const short8*)(W1h + (size_t)(nt * 5 + kt) * 512))[lane];
                short8 bl = ((const short8*)(W1l + (size_t)(nt * 5 + kt) * 512))[lane];
                #pragma unroll
                for (int m = 0; m < 4; m++) {
                    acc[m] = __builtin_amdgcn_mfma_f32_16x16x32_bf16(af[m][kt], bh, acc[m], 0, 0, 0);
                    acc[m] = __builtin_amdgcn_mfma_f32_16x16x32_bf16(af[m][kt], bl, acc[m], 0, 0, 0);
                }
            }
            #pragma unroll
            for (int m = 0; m < 4; m++)
                #pragma unroll
                for (int r = 0; r < 4; r++)
                    sH1[(m * 16 + quad * 4 + r) * H1_STRIDE + nt * 16 + lc] = f2bf(silu_f(acc[m][r]));
        }
    }
    __syncthreads();

    // ---- GEMM2: H1[64x288] @ W2[288x64] -> silu -> m (sM).  Wave w owns nt=w. ----
    {
        int nt = wid;
        float bias = b2[nt * 16 + lc];
        float4v acc[4];
        #pragma unroll
        for (int m = 0; m < 4; m++) acc[m] = (float4v){bias, bias, bias, bias};
        #pragma unroll
        for (int kt = 0; kt < 9; kt++) {
            short8 bh = ((const short8*)(W2h + (size_t)(nt * 9 + kt) * 512))[lane];
            short8 bl = ((const short8*)(W2l + (size_t)(nt * 9 + kt) * 512))[lane];
            #pragma unroll
            for (int m = 0; m < 4; m++) {
                short8 a = *(const short8*)(sH1 + (m * 16 + lc) * H1_STRIDE + kt * 32 + quad * 8);
                acc[m] = __builtin_amdgcn_mfma_f32_16x16x32_bf16(a, bh, acc[m], 0, 0, 0);
                acc[m] = __builtin_amdgcn_mfma_f32_16x16x32_bf16(a, bl, acc[m], 0, 0, 0);
            }
        }
        #pragma unroll
        for (int m = 0; m < 4; m++)
            #pragma unroll
            for (int r = 0; r < 4; r++)
                sM[(m * 16 + quad * 4 + r) * M_STRIDE + nt * 16 + lc] = f2bf(silu_f(acc[m][r]));
    }
    __syncthreads();

    // ---- m tile -> global (sequential CSR slots, coalesced) ----
    {
        int row = t >> 2, c0 = (t & 3) * 16;
        short8 v0 = *(const short8*)(sM + row * M_STRIDE + c0);
        short8 v1 = *(const short8*)(sM + row * M_STRIDE + c0 + 8);
        short* mg = (short*)m_edge + (size_t)(k0 + row) * FH + c0;
        *(short8*)(mg) = v0;
        *(short8*)(mg + 8) = v1;
    }

    // ---- GEMM3 + dot (waves split N, partial cw -> LDS) ----
    {
        short8 ag[4][2];
        #pragma unroll
        for (int m = 0; m < 4; m++)
            #pragma unroll
            for (int kt = 0; kt < 2; kt++)
                ag[m][kt] = *(const short8*)(sM + (m * 16 + lc) * M_STRIDE + kt * 32 + quad * 8);
        float cwpart[4][4];
        #pragma unroll
        for (int m = 0; m < 4; m++)
            #pragma unroll
            for (int r = 0; r < 4; r++) cwpart[m][r] = 0.f;
        for (int nt = wid; nt < 16; nt += 4) {
            float bias = cb1[nt * 16 + lc];
            float4v acc[4];
            #pragma unroll
            for (int m = 0; m < 4; m++) acc[m] = (float4v){bias, bias, bias, bias};
            #pragma unroll
            for (int kt = 0; kt < 2; kt++) {
                short8 bh = ((const short8*)(cW1h + (size_t)(nt * 2 + kt) * 512))[lane];
                short8 bl = ((const short8*)(cW1l + (size_t)(nt * 2 + kt) * 512))[lane];
                #pragma unroll
                for (int m = 0; m < 4; m++) {
                    acc[m] = __builtin_amdgcn_mfma_f32_16x16x32_bf16(ag[m][kt], bh, acc[m], 0, 0, 0);
                    acc[m] = __builtin_amdgcn_mfma_f32_16x16x32_bf16(ag[m][kt], bl, acc[m], 0, 0, 0);
                }
            }
            float wv = cW2[nt * 16 + lc];
            #pragma unroll
            for (int m = 0; m < 4; m++)
                #pragma unroll
                for (int r = 0; r < 4; r++) {
                    float p = silu_f(acc[m][r]) * wv;
                    p += __shfl_xor(p, 1);
                    p += __shfl_xor(p, 2);
                    p += __shfl_xor(p, 4);
                    p += __shfl_xor(p, 8);
                    cwpart[m][r] += p;
                }
        }
        if (lc == 0) {
            #pragma unroll
            for (int m = 0; m < 4; m++)
                #pragma unroll
                for (int r = 0; r < 4; r++)
                    cwbuf[wid * 64 + m * 16 + quad * 4 + r] = cwpart[m][r];
        }
    }
    __syncthreads();

    if (t < 64) {
        float cw = cb2[0] + cwbuf[t] + cwbuf[64 + t] + cwbuf[128 + t] + cwbuf[192 + t];
        float* o = cwrel + (size_t)(k0 + t) * 3;
        o[0] = cw * sRel[t * 3 + 0];
        o[1] = cw * sRel[t * 3 + 1];
        o[2] = cw * sRel[t * 3 + 2];
    }
}

// ---------------- streaming aggregation (CSR-ordered inputs) ----------------
__global__ __launch_bounds__(256) void agg_kernel(
    const int* __restrict__ off, const __hip_bfloat16* __restrict__ m_edge,
    const float* __restrict__ cwrel, const float* __restrict__ coors_in,
    float* __restrict__ coors_out, __hip_bfloat16* __restrict__ m_i)
{
    int n = blockIdx.x * 4 + (threadIdx.x >> 6);
    int j = threadIdx.x & 63;
    if (n >= NN) return;
    int s = off[n], t_end = off[n + 1];
    float sum = 0.f, cv = 0.f;
    for (int k = s; k < t_end; k++) {
        sum += bf2f(((const short*)m_edge)[(size_t)k * FH + j]);
        if (j < 3) cv += cwrel[(size_t)k * 3 + j];
    }
    ((short*)m_i)[(size_t)n * FH + j] = f2bf(sum);
    if (j < 3) coors_out[n * 3 + j] = coors_in[n * 3 + j] + cv;
}

// ---------------- fused MFMA node MLP ----------------
#define HS 136
__global__ __launch_bounds__(256, 2) void node_fused(
    float* __restrict__ feats, const __hip_bfloat16* __restrict__ m_i,
    const short* __restrict__ W1h, const short* __restrict__ W1l, const float* __restrict__ b1,
    const short* __restrict__ W2h, const short* __restrict__ W2l, const float* __restrict__ b2)
{
    __shared__ short sh[64 * HS];   // h = [feats | m_i] bf16
    __shared__ short sg[64 * HS];   // silu(h@W1+b1)
    int t = threadIdx.x, lane = t & 63, wid = t >> 6, quad = lane >> 4, lc = lane & 15;
    int n0 = blockIdx.x * 64;

    {
        int row = t >> 2, sub = t & 3;
        const float4* fp = (const float4*)(feats + (size_t)(n0 + row) * FH + sub * 16);
        short* d = sh + row * HS + sub * 16;
        #pragma unroll
        for (int i = 0; i < 4; i++) {
            float4 a = fp[i];
            d[i * 4 + 0] = f2bf(a.x); d[i * 4 + 1] = f2bf(a.y);
            d[i * 4 + 2] = f2bf(a.z); d[i * 4 + 3] = f2bf(a.w);
        }
        const short8* mp = (const short8*)((const short*)m_i + (size_t)(n0 + row) * FH + sub * 16);
        *(short8*)(sh + row * HS + 64 + sub * 16) = mp[0];
        *(short8*)(sh + row * HS + 64 + sub * 16 + 8) = mp[1];
    }
    __syncthreads();

    short8 af[4][4];
    #pragma unroll
    for (int m = 0; m < 4; m++)
        #pragma unroll
        for (int kt = 0; kt < 4; kt++)
            af[m][kt] = *(const short8*)(sh + (m * 16 + lc) * HS + kt * 32 + quad * 8);
    for (int nt = wid; nt < 8; nt += 4) {
        float bias = b1[nt * 16 + lc];
        float4v acc[4];
        #pragma unroll
        for (int m = 0; m < 4; m++) acc[m] = (float4v){bias, bias, bias, bias};
        #pragma unroll
        for (int kt = 0; kt < 4; kt++) {
            short8 bh = ((const short8*)(W1h + (size_t)(nt * 4 + kt) * 512))[lane];
            short8 bl = ((const short8*)(W1l + (size_t)(nt * 4 + kt) * 512))[lane];
            #pragma unroll
            for (int m = 0; m < 4; m++) {
                acc[m] = __builtin_amdgcn_mfma_f32_16x16x32_bf16(af[m][kt], bh, acc[m], 0, 0, 0);
                acc[m] = __builtin_amdgcn_mfma_f32_16x16x32_bf16(af[m][kt], bl, acc[m], 0, 0, 0);
            }
        }
        #pragma unroll
        for (int m = 0; m < 4; m++)
            #pragma unroll
            for (int r = 0; r < 4; r++)
                sg[(m * 16 + quad * 4 + r) * HS + nt * 16 + lc] = f2bf(silu_f(acc[m][r]));
    }
    __syncthreads();

    {
        int nt = wid;
        float bias = b2[nt * 16 + lc];
        float4v acc[4];
        #pragma unroll
        for (int m = 0; m < 4; m++) acc[m] = (float4v){bias, bias, bias, bias};
        #pragma unroll
        for (int kt = 0; kt < 4; kt++) {
            short8 bh = ((const short8*)(W2h + (size_t)(nt * 4 + kt) * 512))[lane];
            short8 bl = ((const short8*)(W2l + (size_t)(nt * 4 + kt) * 512))[lane];
            #pragma unroll
            for (int m = 0; m < 4; m++) {
                short8 a = *(const short8*)(sg + (m * 16 + lc) * HS + kt * 32 + quad * 8);
                acc[m] = __builtin_amdgcn_mfma_f32_16x16x32_bf16(a, bh, acc[m], 0, 0, 0);
                acc[m] = __builtin_amdgcn_mfma_f32_16x16x32_bf16(a, bl, acc[m], 0, 0, 0);
            }
        }
        #pragma unroll
        for (int m = 0; m < 4; m++)
            #pragma unroll
            for (int r = 0; r < 4; r++) {
                int row = m * 16 + quad * 4 + r;
                float* fp = &feats[(size_t)(n0 + row) * FH + nt * 16 + lc];
                *fp = *fp + acc[m][r];   // residual in fp32
            }
    }
}

__global__ void final_kernel(const float* __restrict__ feats, const float* __restrict__ linW,
                             const float* __restrict__ linb, float* __restrict__ out) {
    int t = blockIdx.x * 256 + threadIdx.x;
    int n = t >> 6;
    int lane = threadIdx.x & 63;
    if (n >= NN) return;
    float v = feats[(size_t)n * FH + lane] * linW[lane];
    #pragma unroll
    for (int off = 32; off > 0; off >>= 1) v += __shfl_down(v, off);
    if (lane == 0) out[n] = v + linb[0];
}

extern "C" void kernel_launch(void* const* d_in, const int* in_sizes, int n_in,
                              void* d_out, int out_size, void* d_ws, size_t ws_size,
                              hipStream_t stream) {
    const float* x      = (const float*)d_in[0];
    const float* pos    = (const float*)d_in[1];
    const int*   ei     = (const int*)d_in[2];
    const float* eattr  = (const float*)d_in[3];
    const float* embedW = (const float*)d_in[4];
    const float* embedb = (const float*)d_in[5];
    const float* eW1    = (const float*)d_in[6];
    const float* eb1    = (const float*)d_in[7];
    const float* eW2    = (const float*)d_in[8];
    const float* eb2    = (const float*)d_in[9];
    const float* cW1    = (const float*)d_in[10];
    const float* cb1    = (const float*)d_in[11];
    const float* cW2    = (const float*)d_in[12];
    const float* cb2    = (const float*)d_in[13];
    const float* nW1    = (const float*)d_in[14];
    const float* nb1    = (const float*)d_in[15];
    const float* nW2    = (const float*)d_in[16];
    const float* nb2    = (const float*)d_in[17];
    const float* linW   = (const float*)d_in[18];
    const float* linb   = (const float*)d_in[19];
    float* out = (float*)d_out;

    char* wp = (char*)d_ws;
    auto alloc = [&](size_t bytes) { void* p = wp; wp += (bytes + 255) & ~(size_t)255; return p; };

    const int W1F_L  = 17 * 5 * 512;
    const int W2F_L  = 4 * 9 * 512;
    const int CW1F_L = 16 * 2 * 512;
    const int NW1F_L = 8 * 4 * 512;
    const int NW2F_L = 4 * 4 * 512;

    float* feats  = (float*)alloc((size_t)NNP * FH * 4);
    __hip_bfloat16* m_i = (__hip_bfloat16*)alloc((size_t)NNP * FH * 2);
    float* cA     = (float*)alloc((size_t)NN * 3 * 4);
    float* cB     = (float*)alloc((size_t)NN * 3 * 4);
    short* W1fh   = (short*)alloc((size_t)3 * W1F_L * 2);
    short* W1fl   = (short*)alloc((size_t)3 * W1F_L * 2);
    short* W2fh   = (short*)alloc((size_t)3 * W2F_L * 2);
    short* W2fl   = (short*)alloc((size_t)3 * W2F_L * 2);
    short* cW1fh  = (short*)alloc((size_t)3 * CW1F_L * 2);
    short* cW1fl  = (short*)alloc((size_t)3 * CW1F_L * 2);
    short* nW1fh  = (short*)alloc((size_t)3 * NW1F_L * 2);
    short* nW1fl  = (short*)alloc((size_t)3 * NW1F_L * 2);
    short* nW2fh  = (short*)alloc((size_t)3 * NW2F_L * 2);
    short* nW2fl  = (short*)alloc((size_t)3 * NW2F_L * 2);
    float* b1p    = (float*)alloc((size_t)3 * 272 * 4);
    int*   deg    = (int*)alloc((size_t)NN * 4);
    int*   off    = (int*)alloc((size_t)(NN + 1) * 4);
    int*   cursor = (int*)alloc((size_t)NN * 4);
    int*   erow   = (int*)alloc((size_t)NE * 4);
    int*   ecol   = (int*)alloc((size_t)NE * 4);
    float* eattrp = (float*)alloc((size_t)NE * 4);
    __hip_bfloat16* m_edge = (__hip_bfloat16*)alloc((size_t)NE * FH * 2);
    float* cwrel  = (float*)alloc((size_t)NE * 3 * 4);

    // weight prep (one launch per matrix, all 3 layers)
    frag_prep2<<<(3 * W1F_L + 255) / 256, 256, 0, stream>>>(
        eW1, W1fh, W1fl, 131, 260, 5, 130, W1F_L, 130 * 260, 3 * W1F_L);
    frag_prep2<<<(3 * W2F_L + 255) / 256, 256, 0, stream>>>(
        eW2, W2fh, W2fl, 260, 64, 9, -1, W2F_L, 260 * 64, 3 * W2F_L);
    frag_prep2<<<(3 * CW1F_L + 255) / 256, 256, 0, stream>>>(
        cW1, cW1fh, cW1fl, 64, 256, 2, -1, CW1F_L, 64 * 256, 3 * CW1F_L);
    frag_prep2<<<(3 * NW1F_L + 255) / 256, 256, 0, stream>>>(
        nW1, nW1fh, nW1fl, 128, 128, 4, -1, NW1F_L, 128 * 128, 3 * NW1F_L);
    frag_prep2<<<(3 * NW2F_L + 255) / 256, 256, 0, stream>>>(
        nW2, nW2fh, nW2fl, 128, 64, 4, -1, NW2F_L, 128 * 64, 3 * NW2F_L);
    pad_b1<<<(3 * 272 + 255) / 256, 256, 0, stream>>>(eb1, b1p);

    // CSR build (edge_index constant across layers)
    hipMemsetAsync(deg, 0, (size_t)NN * 4, stream);
    hist_kernel<<<(NE + 255) / 256, 256, 0, stream>>>(ei, deg);
    scan_kernel<<<1, 1024, 0, stream>>>(deg, off, cursor);
    fill_kernel<<<(NE + 255) / 256, 256, 0, stream>>>(ei, eattr, cursor, erow, ecol, eattrp);

    embed_kernel<<<(NN * FH + 255) / 256, 256, 0, stream>>>(x, embedW, embedb, feats);
    hipMemcpyAsync(cA, pos, (size_t)NN * 3 * 4, hipMemcpyDeviceToDevice, stream);

    float* ccur = cA;
    float* cnext = cB;
    for (int l = 0; l < 3; l++) {
        edge_fused<<<NE / 64, 256, 0, stream>>>(
            erow, ecol, eattrp, feats, ccur,
            W1fh + (size_t)l * W1F_L, W1fl + (size_t)l * W1F_L, b1p + l * 272,
            W2fh + (size_t)l * W2F_L, W2fl + (size_t)l * W2F_L, eb2 + l * 64,
            cW1fh + (size_t)l * CW1F_L, cW1fl + (size_t)l * CW1F_L, cb1 + l * 256,
            cW2 + l * 256, cb2 + l,
            m_edge, cwrel);
        agg_kernel<<<(NN + 3) / 4, 256, 0, stream>>>(
            off, m_edge, cwrel, ccur, cnext, m_i);
        node_fused<<<NNP / 64, 256, 0, stream>>>(
            feats, m_i,
            nW1fh + (size_t)l * NW1F_L, nW1fl + (size_t)l * NW1F_L, nb1 + l * 128,
            nW2fh + (size_t)l * NW2F_L, nW2fl + (size_t)l * NW2F_L, nb2 + l * 64);
        float* tmp = ccur; ccur = cnext; cnext = tmp;
    }
    final_kernel<<<(NN * FH) / 256, 256, 0, stream>>>(feats, linW, linb, out);
}

// Round 6
// 863.230 us; speedup vs baseline: 13.1579x; 1.2261x over previous
//
#include <hip/hip_runtime.h>
#include <hip/hip_bf16.h>

#define NN 50000
#define NNP 50048   // padded to 64-node blocks
#define NE 400000
#define FH 64

typedef __attribute__((ext_vector_type(8))) short short8;
typedef __attribute__((ext_vector_type(4))) float float4v;

__device__ __forceinline__ float silu_f(float x) {
    return x * __builtin_amdgcn_rcpf(1.0f + __expf(-x));
}
__device__ __forceinline__ short f2bf(float f) {
    __hip_bfloat16 h = __float2bfloat16(f);
    return *(short*)&h;
}
__device__ __forceinline__ float bf2f(short s) {
    __hip_bfloat16 h = *(__hip_bfloat16*)&s;
    return __bfloat162float(h);
}

// ---------------- mega weight prep ----------------
// src float [L][K][N] -> hi/lo bf16 frag pairs, frag(nt,kt) at (nt*KT+kt)*512,
// element (lane,j) = W[kt*32+(lane>>4)*8+j][nt*16+(lane&15)], zero-padded.
__device__ __forceinline__ void frag_body(const float* __restrict__ src,
                                          short* __restrict__ hi, short* __restrict__ lo,
                                          int t, int K, int N, int KT, int dup,
                                          int perL, int srcL) {
    int l = t / perL, tt = t - l * perL;
    int j = tt & 7, lane = (tt >> 3) & 63, frag = tt >> 9;
    int nt = frag / KT, kt = frag - nt * KT;
    int k = kt * 32 + ((lane >> 4) << 3) + j;
    int n = nt * 16 + (lane & 15);
    if (k == dup) k = dup - 1;
    float v = (k < K && n < N) ? src[(size_t)l * srcL + k * N + n] : 0.f;
    short h = f2bf(v);
    hi[t] = h;
    lo[t] = f2bf(v - bf2f(h));
}

__global__ void prep_all(const float* __restrict__ eW1, const float* __restrict__ eW2,
                         const float* __restrict__ cW1, const float* __restrict__ nW1,
                         const float* __restrict__ nW2, const float* __restrict__ eb1,
                         short* W1fh, short* W1fl, short* W2fh, short* W2fl,
                         short* cW1fh, short* cW1fl, short* nW1fh, short* nW1fl,
                         short* nW2fh, short* nW2fl, float* b1p) {
    int t = blockIdx.x * 256 + threadIdx.x;
    if (t < 130560) { frag_body(eW1, W1fh, W1fl, t, 131, 260, 5, 130, 43520, 33800); return; }
    t -= 130560;
    if (t < 55296) { frag_body(eW2, W2fh, W2fl, t, 260, 64, 9, -1, 18432, 16640); return; }
    t -= 55296;
    if (t < 49152) { frag_body(cW1, cW1fh, cW1fl, t, 64, 256, 2, -1, 16384, 16384); return; }
    t -= 49152;
    if (t < 49152) { frag_body(nW1, nW1fh, nW1fl, t, 128, 128, 4, -1, 16384, 16384); return; }
    t -= 49152;
    if (t < 24576) { frag_body(nW2, nW2fh, nW2fl, t, 128, 64, 4, -1, 8192, 8192); return; }
    t -= 24576;
    if (t < 816) { int l = t / 272, c = t - l * 272; b1p[t] = (c < 260) ? eb1[l * 260 + c] : 0.f; }
}

__global__ void embed_kernel(const float* __restrict__ x, const float* __restrict__ W,
                             const float* __restrict__ b, const float* __restrict__ pos,
                             float* __restrict__ feats, __hip_bfloat16* __restrict__ featsb,
                             float* __restrict__ cA) {
    int t = blockIdx.x * 256 + threadIdx.x;
    if (t >= NN * FH) return;
    int n = t >> 6, hcol = t & 63;
    float acc = b[hcol];
    #pragma unroll
    for (int k = 0; k < 8; k++) acc += x[n * 8 + k] * W[k * FH + hcol];
    feats[t] = acc;
    ((short*)featsb)[t] = f2bf(acc);
    if (hcol < 3) cA[n * 3 + hcol] = pos[n * 3 + hcol];
}

// ---------------- CSR build ----------------
__global__ void hist_kernel(const int* __restrict__ ei, int* __restrict__ deg) {
    int e = blockIdx.x * 256 + threadIdx.x;
    if (e >= NE) return;
    atomicAdd(&deg[ei[e]], 1);
}

__global__ void scan_kernel(const int* __restrict__ deg, int* __restrict__ off,
                            int* __restrict__ cursor) {
    __shared__ int sa[1024], sb[1024];
    int t = threadIdx.x;
    const int CH = (NN + 1023) / 1024;
    int base = t * CH;
    int s = 0;
    for (int i = 0; i < CH; i++) {
        int idx = base + i;
        if (idx < NN) s += deg[idx];
    }
    sa[t] = s;
    __syncthreads();
    int* src = sa; int* dst = sb;
    for (int d = 1; d < 1024; d <<= 1) {
        dst[t] = src[t] + ((t >= d) ? src[t - d] : 0);
        __syncthreads();
        int* tmp = src; src = dst; dst = tmp;
    }
    int run = (t == 0) ? 0 : src[t - 1];
    for (int i = 0; i < CH; i++) {
        int idx = base + i;
        if (idx < NN) { off[idx] = run; cursor[idx] = run; run += deg[idx]; }
    }
    if (t == 1023) off[NN] = src[1023];
}

__global__ void fill_kernel(const int* __restrict__ ei, const float* __restrict__ eattr,
                            int* __restrict__ cursor, int* __restrict__ erow,
                            int* __restrict__ ecol, float* __restrict__ eattrp) {
    int e = blockIdx.x * 256 + threadIdx.x;
    if (e >= NE) return;
    int r = ei[e];
    int p = atomicAdd(&cursor[r], 1);
    erow[p] = r;
    ecol[p] = ei[NE + e];
    eattrp[p] = eattr[e];
}

// ---------------- fused MFMA edge pipeline (LDS overlay, 3 blocks/CU) ----------------
#define SE_STRIDE 168   // shorts
#define H1_STRIDE 296
#define M_STRIDE  72

__global__ __launch_bounds__(256, 3) void edge_fused(
    const int* __restrict__ erow, const int* __restrict__ ecol,
    const float* __restrict__ eattrp,
    const __hip_bfloat16* __restrict__ featsb, const float* __restrict__ coors,
    const short* __restrict__ W1h, const short* __restrict__ W1l, const float* __restrict__ b1p,
    const short* __restrict__ W2h, const short* __restrict__ W2l, const float* __restrict__ b2,
    const short* __restrict__ cW1h, const short* __restrict__ cW1l, const float* __restrict__ cb1,
    const float* __restrict__ cW2, const float* __restrict__ cb2,
    __hip_bfloat16* __restrict__ m_edge, float* __restrict__ cwrel)
{
    // single base array: sH1 legally aliases sE, so the compiler cannot sink
    // the af ds_reads past the GEMM1 stores (overlay correctness).
    __shared__ char smem[48896];
    short* sE   = (short*)smem;               // [0,21504)  live: gather -> af load
    short* sH1  = (short*)smem;               // [0,37888)  live: GEMM1 -> GEMM2 (overlays sE)
    short* sM   = (short*)(smem + 37888);     // [37888,47104)
    float* sRel = (float*)(smem + 47104);     // 768 B, live whole kernel
    float* cwbuf = (float*)(smem + 47872);    // 1024 B

    int t = threadIdx.x;
    int k0 = blockIdx.x * 64;
    int lane = t & 63, wid = t >> 6, quad = lane >> 4, lc = lane & 15;

    // ---- phase 1: gather e_in (bf16 feats mirror -> pure copies) ----
    {
        int el = t >> 2, sub = t & 3, k = k0 + el;
        int rI = erow[k], cI = ecol[k];
        const short8* fr = (const short8*)((const short*)featsb + (size_t)rI * FH);
        const short8* fc = (const short8*)((const short*)featsb + (size_t)cI * FH);
        short* er = sE + el * SE_STRIDE;
        *(short8*)(er + sub * 16) = fr[sub * 2];
        *(short8*)(er + sub * 16 + 8) = fr[sub * 2 + 1];
        *(short8*)(er + 64 + sub * 16) = fc[sub * 2];
        *(short8*)(er + 64 + sub * 16 + 8) = fc[sub * 2 + 1];
        #pragma unroll
        for (int i = 0; i < 10; i++) er[128 + sub * 10 + i] = 0;
        if (sub == 0) {
            float rx = coors[rI * 3 + 0] - coors[cI * 3 + 0];
            float ry = coors[rI * 3 + 1] - coors[cI * 3 + 1];
            float rz = coors[rI * 3 + 2] - coors[cI * 3 + 2];
            float dist = rx * rx + ry * ry + rz * rz;
            short dh = f2bf(dist);
            er[128] = f2bf(eattrp[k]);
            er[129] = dh;
            er[130] = f2bf(dist - bf2f(dh));
            sRel[el * 3 + 0] = rx; sRel[el * 3 + 1] = ry; sRel[el * 3 + 2] = rz;
        }
    }
    __syncthreads();

    // ---- phase 2: all waves load A fragments, then fence before overlay ----
    short8 af[4][5];
    #pragma unroll
    for (int m = 0; m < 4; m++)
        #pragma unroll
        for (int kt = 0; kt < 5; kt++)
            af[m][kt] = *(const short8*)(sE + (m * 16 + lc) * SE_STRIDE + kt * 32 + quad * 8);
    __syncthreads();

    // ---- phase 3: GEMM1 e_in[64x160] @ W1[160x272] -> silu -> sH1 ----
    {
        // zero H1 pad cols [272,288)
        *(long long*)(sH1 + (t >> 2) * H1_STRIDE + 272 + (t & 3) * 4) = 0LL;
        for (int nt = wid; nt < 17; nt += 4) {
            float bias = b1p[nt * 16 + lc];
            float4v acc[4];
            #pragma unroll
            for (int m = 0; m < 4; m++) acc[m] = (float4v){bias, bias, bias, bias};
            #pragma unroll
            for (int kt = 0; kt < 5; kt++) {
                short8 bh = ((const short8*)(W1h + (size_t)(nt * 5 + kt) * 512))[lane];
                short8 bl = ((const short8*)(W1l + (size_t)(nt * 5 + kt) * 512))[lane];
                #pragma unroll
                for (int m = 0; m < 4; m++) {
                    acc[m] = __builtin_amdgcn_mfma_f32_16x16x32_bf16(af[m][kt], bh, acc[m], 0, 0, 0);
                    acc[m] = __builtin_amdgcn_mfma_f32_16x16x32_bf16(af[m][kt], bl, acc[m], 0, 0, 0);
                }
            }
            #pragma unroll
            for (int m = 0; m < 4; m++)
                #pragma unroll
                for (int r = 0; r < 4; r++)
                    sH1[(m * 16 + quad * 4 + r) * H1_STRIDE + nt * 16 + lc] = f2bf(silu_f(acc[m][r]));
        }
    }
    __syncthreads();

    // ---- phase 4: GEMM2 H1[64x288] @ W2[288x64] -> silu -> sM ----
    {
        int nt = wid;
        float bias = b2[nt * 16 + lc];
        float4v acc[4];
        #pragma unroll
        for (int m = 0; m < 4; m++) acc[m] = (float4v){bias, bias, bias, bias};
        #pragma unroll
        for (int kt = 0; kt < 9; kt++) {
            short8 bh = ((const short8*)(W2h + (size_t)(nt * 9 + kt) * 512))[lane];
            short8 bl = ((const short8*)(W2l + (size_t)(nt * 9 + kt) * 512))[lane];
            #pragma unroll
            for (int m = 0; m < 4; m++) {
                short8 a = *(const short8*)(sH1 + (m * 16 + lc) * H1_STRIDE + kt * 32 + quad * 8);
                acc[m] = __builtin_amdgcn_mfma_f32_16x16x32_bf16(a, bh, acc[m], 0, 0, 0);
                acc[m] = __builtin_amdgcn_mfma_f32_16x16x32_bf16(a, bl, acc[m], 0, 0, 0);
            }
        }
        #pragma unroll
        for (int m = 0; m < 4; m++)
            #pragma unroll
            for (int r = 0; r < 4; r++)
                sM[(m * 16 + quad * 4 + r) * M_STRIDE + nt * 16 + lc] = f2bf(silu_f(acc[m][r]));
    }
    __syncthreads();

    // ---- phase 5: m -> global + GEMM3 (deferred cross-lane reduce) ----
    {
        int row = t >> 2, c0 = (t & 3) * 16;
        short8 v0 = *(const short8*)(sM + row * M_STRIDE + c0);
        short8 v1 = *(const short8*)(sM + row * M_STRIDE + c0 + 8);
        short* mg = (short*)m_edge + (size_t)(k0 + row) * FH + c0;
        *(short8*)(mg) = v0;
        *(short8*)(mg + 8) = v1;
    }
    {
        short8 ag[4][2];
        #pragma unroll
        for (int m = 0; m < 4; m++)
            #pragma unroll
            for (int kt = 0; kt < 2; kt++)
                ag[m][kt] = *(const short8*)(sM + (m * 16 + lc) * M_STRIDE + kt * 32 + quad * 8);
        float cwpart[4][4];
        #pragma unroll
        for (int m = 0; m < 4; m++)
            #pragma unroll
            for (int r = 0; r < 4; r++) cwpart[m][r] = 0.f;
        for (int nt = wid; nt < 16; nt += 4) {
            float bias = cb1[nt * 16 + lc];
            float4v acc[4];
            #pragma unroll
            for (int m = 0; m < 4; m++) acc[m] = (float4v){bias, bias, bias, bias};
            #pragma unroll
            for (int kt = 0; kt < 2; kt++) {
                short8 bh = ((const short8*)(cW1h + (size_t)(nt * 2 + kt) * 512))[lane];
                short8 bl = ((const short8*)(cW1l + (size_t)(nt * 2 + kt) * 512))[lane];
                #pragma unroll
                for (int m = 0; m < 4; m++) {
                    acc[m] = __builtin_amdgcn_mfma_f32_16x16x32_bf16(ag[m][kt], bh, acc[m], 0, 0, 0);
                    acc[m] = __builtin_amdgcn_mfma_f32_16x16x32_bf16(ag[m][kt], bl, acc[m], 0, 0, 0);
                }
            }
            float wv = cW2[nt * 16 + lc];
            #pragma unroll
            for (int m = 0; m < 4; m++)
                #pragma unroll
                for (int r = 0; r < 4; r++)
                    cwpart[m][r] += silu_f(acc[m][r]) * wv;
        }
        #pragma unroll
        for (int m = 0; m < 4; m++)
            #pragma unroll
            for (int r = 0; r < 4; r++) {
                float p = cwpart[m][r];
                p += __shfl_xor(p, 1);
                p += __shfl_xor(p, 2);
                p += __shfl_xor(p, 4);
                p += __shfl_xor(p, 8);
                if (lc == 0) cwbuf[wid * 64 + m * 16 + quad * 4 + r] = p;
            }
    }
    __syncthreads();

    if (t < 64) {
        float cw = cb2[0] + cwbuf[t] + cwbuf[64 + t] + cwbuf[128 + t] + cwbuf[192 + t];
        float* o = cwrel + (size_t)(k0 + t) * 3;
        o[0] = cw * sRel[t * 3 + 0];
        o[1] = cw * sRel[t * 3 + 1];
        o[2] = cw * sRel[t * 3 + 2];
    }
}

// ---------------- streaming aggregation (CSR-ordered inputs) ----------------
__global__ __launch_bounds__(256) void agg_kernel(
    const int* __restrict__ off, const __hip_bfloat16* __restrict__ m_edge,
    const float* __restrict__ cwrel, const float* __restrict__ coors_in,
    float* __restrict__ coors_out, __hip_bfloat16* __restrict__ m_i)
{
    int n = blockIdx.x * 4 + (threadIdx.x >> 6);
    int j = threadIdx.x & 63;
    if (n >= NN) return;
    int s = off[n], t_end = off[n + 1];
    float sum = 0.f, cv = 0.f;
    for (int k = s; k < t_end; k++) {
        sum += bf2f(((const short*)m_edge)[(size_t)k * FH + j]);
        if (j < 3) cv += cwrel[(size_t)k * 3 + j];
    }
    ((short*)m_i)[(size_t)n * FH + j] = f2bf(sum);
    if (j < 3) coors_out[n * 3 + j] = coors_in[n * 3 + j] + cv;
}

// ---------------- fused MFMA node MLP ----------------
#define HS 136
__global__ __launch_bounds__(256, 4) void node_fused(
    float* __restrict__ feats, __hip_bfloat16* __restrict__ featsb,
    const __hip_bfloat16* __restrict__ m_i,
    const short* __restrict__ W1h, const short* __restrict__ W1l, const float* __restrict__ b1,
    const short* __restrict__ W2h, const short* __restrict__ W2l, const float* __restrict__ b2)
{
    __shared__ short sh[64 * HS];   // h = [featsb | m_i]
    __shared__ short sg[64 * HS];   // silu(h@W1+b1)
    int t = threadIdx.x, lane = t & 63, wid = t >> 6, quad = lane >> 4, lc = lane & 15;
    int n0 = blockIdx.x * 64;

    {
        int row = t >> 2, sub = t & 3;
        const short8* fp = (const short8*)((const short*)featsb + (size_t)(n0 + row) * FH);
        *(short8*)(sh + row * HS + sub * 16) = fp[sub * 2];
        *(short8*)(sh + row * HS + sub * 16 + 8) = fp[sub * 2 + 1];
        const short8* mp = (const short8*)((const short*)m_i + (size_t)(n0 + row) * FH);
        *(short8*)(sh + row * HS + 64 + sub * 16) = mp[sub * 2];
        *(short8*)(sh + row * HS + 64 + sub * 16 + 8) = mp[sub * 2 + 1];
    }
    __syncthreads();

    short8 af[4][4];
    #pragma unroll
    for (int m = 0; m < 4; m++)
        #pragma unroll
        for (int kt = 0; kt < 4; kt++)
            af[m][kt] = *(const short8*)(sh + (m * 16 + lc) * HS + kt * 32 + quad * 8);
    for (int nt = wid; nt < 8; nt += 4) {
        float bias = b1[nt * 16 + lc];
        float4v acc[4];
        #pragma unroll
        for (int m = 0; m < 4; m++) acc[m] = (float4v){bias, bias, bias, bias};
        #pragma unroll
        for (int kt = 0; kt < 4; kt++) {
            short8 bh = ((const short8*)(W1h + (size_t)(nt * 4 + kt) * 512))[lane];
            short8 bl = ((const short8*)(W1l + (size_t)(nt * 4 + kt) * 512))[lane];
            #pragma unroll
            for (int m = 0; m < 4; m++) {
                acc[m] = __builtin_amdgcn_mfma_f32_16x16x32_bf16(af[m][kt], bh, acc[m], 0, 0, 0);
                acc[m] = __builtin_amdgcn_mfma_f32_16x16x32_bf16(af[m][kt], bl, acc[m], 0, 0, 0);
            }
        }
        #pragma unroll
        for (int m = 0; m < 4; m++)
            #pragma unroll
            for (int r = 0; r < 4; r++)
                sg[(m * 16 + quad * 4 + r) * HS + nt * 16 + lc] = f2bf(silu_f(acc[m][r]));
    }
    __syncthreads();

    {
        int nt = wid;
        float bias = b2[nt * 16 + lc];
        float4v acc[4];
        #pragma unroll
        for (int m = 0; m < 4; m++) acc[m] = (float4v){bias, bias, bias, bias};
        #pragma unroll
        for (int kt = 0; kt < 4; kt++) {
            short8 bh = ((const short8*)(W2h + (size_t)(nt * 4 + kt) * 512))[lane];
            short8 bl = ((const short8*)(W2l + (size_t)(nt * 4 + kt) * 512))[lane];
            #pragma unroll
            for (int m = 0; m < 4; m++) {
                short8 a = *(const short8*)(sg + (m * 16 + lc) * HS + kt * 32 + quad * 8);
                acc[m] = __builtin_amdgcn_mfma_f32_16x16x32_bf16(a, bh, acc[m], 0, 0, 0);
                acc[m] = __builtin_amdgcn_mfma_f32_16x16x32_bf16(a, bl, acc[m], 0, 0, 0);
            }
        }
        #pragma unroll
        for (int m = 0; m < 4; m++)
            #pragma unroll
            for (int r = 0; r < 4; r++) {
                int row = m * 16 + quad * 4 + r;
                size_t idx = (size_t)(n0 + row) * FH + nt * 16 + lc;
                float nv = feats[idx] + acc[m][r];   // residual in fp32
                feats[idx] = nv;
                ((short*)featsb)[idx] = f2bf(nv);
            }
    }
}

__global__ void final_kernel(const float* __restrict__ feats, const float* __restrict__ linW,
                             const float* __restrict__ linb, float* __restrict__ out) {
    int t = blockIdx.x * 256 + threadIdx.x;
    int n = t >> 6;
    int lane = threadIdx.x & 63;
    if (n >= NN) return;
    float v = feats[(size_t)n * FH + lane] * linW[lane];
    #pragma unroll
    for (int off = 32; off > 0; off >>= 1) v += __shfl_down(v, off);
    if (lane == 0) out[n] = v + linb[0];
}

extern "C" void kernel_launch(void* const* d_in, const int* in_sizes, int n_in,
                              void* d_out, int out_size, void* d_ws, size_t ws_size,
                              hipStream_t stream) {
    const float* x      = (const float*)d_in[0];
    const float* pos    = (const float*)d_in[1];
    const int*   ei     = (const int*)d_in[2];
    const float* eattr  = (const float*)d_in[3];
    const float* embedW = (const float*)d_in[4];
    const float* embedb = (const float*)d_in[5];
    const float* eW1    = (const float*)d_in[6];
    const float* eb1    = (const float*)d_in[7];
    const float* eW2    = (const float*)d_in[8];
    const float* eb2    = (const float*)d_in[9];
    const float* cW1    = (const float*)d_in[10];
    const float* cb1    = (const float*)d_in[11];
    const float* cW2    = (const float*)d_in[12];
    const float* cb2    = (const float*)d_in[13];
    const float* nW1    = (const float*)d_in[14];
    const float* nb1    = (const float*)d_in[15];
    const float* nW2    = (const float*)d_in[16];
    const float* nb2    = (const float*)d_in[17];
    const float* linW   = (const float*)d_in[18];
    const float* linb   = (const float*)d_in[19];
    float* out = (float*)d_out;

    char* wp = (char*)d_ws;
    auto alloc = [&](size_t bytes) { void* p = wp; wp += (bytes + 255) & ~(size_t)255; return p; };

    const int W1F_L  = 17 * 5 * 512;
    const int W2F_L  = 4 * 9 * 512;
    const int CW1F_L = 16 * 2 * 512;
    const int NW1F_L = 8 * 4 * 512;
    const int NW2F_L = 4 * 4 * 512;

    float* feats  = (float*)alloc((size_t)NNP * FH * 4);
    __hip_bfloat16* featsb = (__hip_bfloat16*)alloc((size_t)NNP * FH * 2);
    __hip_bfloat16* m_i = (__hip_bfloat16*)alloc((size_t)NNP * FH * 2);
    float* cA     = (float*)alloc((size_t)NN * 3 * 4);
    float* cB     = (float*)alloc((size_t)NN * 3 * 4);
    short* W1fh   = (short*)alloc((size_t)3 * W1F_L * 2);
    short* W1fl   = (short*)alloc((size_t)3 * W1F_L * 2);
    short* W2fh   = (short*)alloc((size_t)3 * W2F_L * 2);
    short* W2fl   = (short*)alloc((size_t)3 * W2F_L * 2);
    short* cW1fh  = (short*)alloc((size_t)3 * CW1F_L * 2);
    short* cW1fl  = (short*)alloc((size_t)3 * CW1F_L * 2);
    short* nW1fh  = (short*)alloc((size_t)3 * NW1F_L * 2);
    short* nW1fl  = (short*)alloc((size_t)3 * NW1F_L * 2);
    short* nW2fh  = (short*)alloc((size_t)3 * NW2F_L * 2);
    short* nW2fl  = (short*)alloc((size_t)3 * NW2F_L * 2);
    float* b1p    = (float*)alloc((size_t)3 * 272 * 4);
    int*   deg    = (int*)alloc((size_t)NN * 4);
    int*   off    = (int*)alloc((size_t)(NN + 1) * 4);
    int*   cursor = (int*)alloc((size_t)NN * 4);
    int*   erow   = (int*)alloc((size_t)NE * 4);
    int*   ecol   = (int*)alloc((size_t)NE * 4);
    float* eattrp = (float*)alloc((size_t)NE * 4);
    __hip_bfloat16* m_edge = (__hip_bfloat16*)alloc((size_t)NE * FH * 2);
    float* cwrel  = (float*)alloc((size_t)NE * 3 * 4);

    // mega weight prep: 309552 work items
    prep_all<<<(309552 + 255) / 256, 256, 0, stream>>>(
        eW1, eW2, cW1, nW1, nW2, eb1,
        W1fh, W1fl, W2fh, W2fl, cW1fh, cW1fl, nW1fh, nW1fl, nW2fh, nW2fl, b1p);

    // CSR build (edge_index constant across layers)
    hipMemsetAsync(deg, 0, (size_t)NN * 4, stream);
    hist_kernel<<<(NE + 255) / 256, 256, 0, stream>>>(ei, deg);
    scan_kernel<<<1, 1024, 0, stream>>>(deg, off, cursor);
    fill_kernel<<<(NE + 255) / 256, 256, 0, stream>>>(ei, eattr, cursor, erow, ecol, eattrp);

    embed_kernel<<<(NN * FH + 255) / 256, 256, 0, stream>>>(x, embedW, embedb, pos, feats, featsb, cA);

    float* ccur = cA;
    float* cnext = cB;
    for (int l = 0; l < 3; l++) {
        edge_fused<<<NE / 64, 256, 0, stream>>>(
            erow, ecol, eattrp, featsb, ccur,
            W1fh + (size_t)l * W1F_L, W1fl + (size_t)l * W1F_L, b1p + l * 272,
            W2fh + (size_t)l * W2F_L, W2fl + (size_t)l * W2F_L, eb2 + l * 64,
            cW1fh + (size_t)l * CW1F_L, cW1fl + (size_t)l * CW1F_L, cb1 + l * 256,
            cW2 + l * 256, cb2 + l,
            m_edge, cwrel);
        agg_kernel<<<(NN + 3) / 4, 256, 0, stream>>>(
            off, m_edge, cwrel, ccur, cnext, m_i);
        node_fused<<<NNP / 64, 256, 0, stream>>>(
            feats, featsb, m_i,
            nW1fh + (size_t)l * NW1F_L, nW1fl + (size_t)l * NW1F_L, nb1 + l * 128,
            nW2fh + (size_t)l * NW2F_L, nW2fl + (size_t)l * NW2F_L, nb2 + l * 64);
        float* tmp = ccur; ccur = cnext; cnext = tmp;
    }
    final_kernel<<<(NN * FH) / 256, 256, 0, stream>>>(feats, linW, linb, out);
}

// Round 7
// 841.266 us; speedup vs baseline: 13.5015x; 1.0261x over previous
//
#include <hip/hip_runtime.h>
#include <hip/hip_bf16.h>

#define NN 50000
#define NNP 50048   // padded to 64-node blocks
#define NE 400000
#define FH 64

typedef __attribute__((ext_vector_type(8))) short short8;
typedef __attribute__((ext_vector_type(4))) float float4v;

__device__ __forceinline__ float silu_f(float x) {
    return x * __builtin_amdgcn_rcpf(1.0f + __expf(-x));
}
__device__ __forceinline__ short f2bf(float f) {
    __hip_bfloat16 h = __float2bfloat16(f);
    return *(short*)&h;
}
__device__ __forceinline__ float bf2f(short s) {
    __hip_bfloat16 h = *(__hip_bfloat16*)&s;
    return __bfloat162float(h);
}

// ---------------- mega weight prep ----------------
__device__ __forceinline__ void frag_body(const float* __restrict__ src,
                                          short* __restrict__ hi, short* __restrict__ lo,
                                          int t, int K, int N, int KT, int dup,
                                          int perL, int srcL) {
    int l = t / perL, tt = t - l * perL;
    int j = tt & 7, lane = (tt >> 3) & 63, frag = tt >> 9;
    int nt = frag / KT, kt = frag - nt * KT;
    int k = kt * 32 + ((lane >> 4) << 3) + j;
    int n = nt * 16 + (lane & 15);
    if (k == dup) k = dup - 1;
    float v = (k < K && n < N) ? src[(size_t)l * srcL + k * N + n] : 0.f;
    short h = f2bf(v);
    hi[t] = h;
    lo[t] = f2bf(v - bf2f(h));
}

__global__ void prep_all(const float* __restrict__ eW1, const float* __restrict__ eW2,
                         const float* __restrict__ cW1, const float* __restrict__ nW1,
                         const float* __restrict__ nW2, const float* __restrict__ eb1,
                         short* W1fh, short* W1fl, short* W2fh, short* W2fl,
                         short* cW1fh, short* cW1fl, short* nW1fh, short* nW1fl,
                         short* nW2fh, short* nW2fl, float* b1p) {
    int t = blockIdx.x * 256 + threadIdx.x;
    if (t < 130560) { frag_body(eW1, W1fh, W1fl, t, 131, 260, 5, 130, 43520, 33800); return; }
    t -= 130560;
    if (t < 55296) { frag_body(eW2, W2fh, W2fl, t, 260, 64, 9, -1, 18432, 16640); return; }
    t -= 55296;
    if (t < 49152) { frag_body(cW1, cW1fh, cW1fl, t, 64, 256, 2, -1, 16384, 16384); return; }
    t -= 49152;
    if (t < 49152) { frag_body(nW1, nW1fh, nW1fl, t, 128, 128, 4, -1, 16384, 16384); return; }
    t -= 49152;
    if (t < 24576) { frag_body(nW2, nW2fh, nW2fl, t, 128, 64, 4, -1, 8192, 8192); return; }
    t -= 24576;
    if (t < 816) { int l = t / 272, c = t - l * 272; b1p[t] = (c < 260) ? eb1[l * 260 + c] : 0.f; }
}

__global__ void embed_kernel(const float* __restrict__ x, const float* __restrict__ W,
                             const float* __restrict__ b, const float* __restrict__ pos,
                             float* __restrict__ feats, __hip_bfloat16* __restrict__ featsb,
                             float* __restrict__ cA) {
    int t = blockIdx.x * 256 + threadIdx.x;
    if (t >= NN * FH) return;
    int n = t >> 6, hcol = t & 63;
    float acc = b[hcol];
    #pragma unroll
    for (int k = 0; k < 8; k++) acc += x[n * 8 + k] * W[k * FH + hcol];
    feats[t] = acc;
    ((short*)featsb)[t] = f2bf(acc);
    if (hcol < 3) cA[n * 3 + hcol] = pos[n * 3 + hcol];
}

// ---------------- CSR build (no serial scan: block scan + global cursor) ----------------
__global__ void hist_kernel(const int* __restrict__ ei, int* __restrict__ deg) {
    int e = blockIdx.x * 256 + threadIdx.x;
    if (e >= NE) return;
    atomicAdd(&deg[ei[e]], 1);
}

__global__ void alloc_kernel(const int* __restrict__ deg, int* __restrict__ off,
                             int* __restrict__ cursor, int* __restrict__ gcount) {
    __shared__ int s[256];
    __shared__ int base;
    int t = threadIdx.x, n = blockIdx.x * 256 + t;
    int d = (n < NN) ? deg[n] : 0;
    s[t] = d;
    __syncthreads();
    for (int st = 1; st < 256; st <<= 1) {
        int v = (t >= st) ? s[t - st] : 0;
        __syncthreads();
        s[t] += v;
        __syncthreads();
    }
    if (t == 255) base = atomicAdd(gcount, s[255]);
    __syncthreads();
    if (n < NN) { int o = base + s[t] - d; off[n] = o; cursor[n] = o; }
}

__global__ void fill_kernel(const int* __restrict__ ei, const float* __restrict__ eattr,
                            int* __restrict__ cursor, int* __restrict__ erow,
                            int* __restrict__ ecol, float* __restrict__ eattrp) {
    int e = blockIdx.x * 256 + threadIdx.x;
    if (e >= NE) return;
    int r = ei[e];
    int p = atomicAdd(&cursor[r], 1);
    erow[p] = r;
    ecol[p] = ei[NE + e];
    eattrp[p] = eattr[e];
}

// ---------------- fused MFMA edge pipeline ----------------
#define SE_STRIDE 168   // shorts
#define H1_STRIDE 296
#define M_STRIDE  72

// XOR bank swizzle: permutes 8-element column blocks by row, keeps b128 alignment
__device__ __forceinline__ int swz(int row, int col) {
    return col ^ (((row >> 2) & 3) << 3);
}

__global__ __launch_bounds__(256, 3) void edge_fused(
    const int* __restrict__ erow, const int* __restrict__ ecol,
    const float* __restrict__ eattrp,
    const __hip_bfloat16* __restrict__ featsb, const float* __restrict__ coors,
    const short* __restrict__ W1h, const short* __restrict__ W1l, const float* __restrict__ b1p,
    const short* __restrict__ W2h, const short* __restrict__ W2l, const float* __restrict__ b2,
    const short* __restrict__ cW1h, const short* __restrict__ cW1l, const float* __restrict__ cb1,
    const float* __restrict__ cW2, const float* __restrict__ cb2,
    __hip_bfloat16* __restrict__ m_edge, float* __restrict__ cwrel)
{
    __shared__ char smem[48896];
    short* sE   = (short*)smem;               // [0,21504)
    short* sH1  = (short*)smem;               // [0,37888) overlays sE
    short* sM   = (short*)(smem + 37888);     // [37888,47104)
    float* sRel = (float*)(smem + 47104);
    float* cwbuf = (float*)(smem + 47872);

    int t = threadIdx.x;
    int k0 = blockIdx.x * 64;
    int lane = t & 63, wid = t >> 6, quad = lane >> 4, lc = lane & 15;

    // ---- phase 1: gather e_in ----
    {
        int el = t >> 2, sub = t & 3, k = k0 + el;
        int rI = erow[k], cI = ecol[k];
        const short8* fr = (const short8*)((const short*)featsb + (size_t)rI * FH);
        const short8* fc = (const short8*)((const short*)featsb + (size_t)cI * FH);
        short* er = sE + el * SE_STRIDE;
        *(short8*)(er + sub * 16) = fr[sub * 2];
        *(short8*)(er + sub * 16 + 8) = fr[sub * 2 + 1];
        *(short8*)(er + 64 + sub * 16) = fc[sub * 2];
        *(short8*)(er + 64 + sub * 16 + 8) = fc[sub * 2 + 1];
        #pragma unroll
        for (int i = 0; i < 10; i++) er[128 + sub * 10 + i] = 0;
        if (sub == 0) {
            float rx = coors[rI * 3 + 0] - coors[cI * 3 + 0];
            float ry = coors[rI * 3 + 1] - coors[cI * 3 + 1];
            float rz = coors[rI * 3 + 2] - coors[cI * 3 + 2];
            float dist = rx * rx + ry * ry + rz * rz;
            short dh = f2bf(dist);
            er[128] = f2bf(eattrp[k]);
            er[129] = dh;
            er[130] = f2bf(dist - bf2f(dh));
            sRel[el * 3 + 0] = rx; sRel[el * 3 + 1] = ry; sRel[el * 3 + 2] = rz;
        }
    }
    __syncthreads();

    // ---- phase 2: A fragments to registers, fence before overlay ----
    short8 af[4][5];
    #pragma unroll
    for (int m = 0; m < 4; m++)
        #pragma unroll
        for (int kt = 0; kt < 5; kt++)
            af[m][kt] = *(const short8*)(sE + (m * 16 + lc) * SE_STRIDE + kt * 32 + quad * 8);
    __syncthreads();

    // ---- phase 3: GEMM1 -> silu -> sH1 (swizzled) ----
    {
        // zero pad cols [272,288) at swizzled positions
        {
            int row = t >> 2, c = 272 + (t & 3) * 4;
            *(long long*)(sH1 + row * H1_STRIDE + swz(row, c)) = 0LL;
        }
        for (int nt = wid; nt < 17; nt += 4) {
            float bias = b1p[nt * 16 + lc];
            float4v acc[4];
            #pragma unroll
            for (int m = 0; m < 4; m++) acc[m] = (float4v){bias, bias, bias, bias};
            #pragma unroll
            for (int kt = 0; kt < 5; kt++) {
                short8 bh = ((const short8*)(W1h + (size_t)(nt * 5 + kt) * 512))[lane];
                short8 bl = ((const short8*)(W1l + (size_t)(nt * 5 + kt) * 512))[lane];
                #pragma unroll
                for (int m = 0; m < 4; m++) {
                    acc[m] = __builtin_amdgcn_mfma_f32_16x16x32_bf16(af[m][kt], bh, acc[m], 0, 0, 0);
                    acc[m] = __builtin_amdgcn_mfma_f32_16x16x32_bf16(af[m][kt], bl, acc[m], 0, 0, 0);
                }
            }
            #pragma unroll
            for (int m = 0; m < 4; m++) {
                int sw = ((m * 4 + quad) & 3) << 3;
                #pragma unroll
                for (int r = 0; r < 4; r++)
                    sH1[(m * 16 + quad * 4 + r) * H1_STRIDE + ((nt * 16 + lc) ^ sw)] = f2bf(silu_f(acc[m][r]));
            }
        }
    }
    __syncthreads();

    // ---- phase 4: GEMM2 -> silu -> sM (swizzled) ----
    {
        int nt = wid;
        float bias = b2[nt * 16 + lc];
        float4v acc[4];
        #pragma unroll
        for (int m = 0; m < 4; m++) acc[m] = (float4v){bias, bias, bias, bias};
        #pragma unroll
        for (int kt = 0; kt < 9; kt++) {
            short8 bh = ((const short8*)(W2h + (size_t)(nt * 9 + kt) * 512))[lane];
            short8 bl = ((const short8*)(W2l + (size_t)(nt * 9 + kt) * 512))[lane];
            #pragma unroll
            for (int m = 0; m < 4; m++) {
                int row = m * 16 + lc;
                short8 a = *(const short8*)(sH1 + row * H1_STRIDE + swz(row, kt * 32 + quad * 8));
                acc[m] = __builtin_amdgcn_mfma_f32_16x16x32_bf16(a, bh, acc[m], 0, 0, 0);
                acc[m] = __builtin_amdgcn_mfma_f32_16x16x32_bf16(a, bl, acc[m], 0, 0, 0);
            }
        }
        #pragma unroll
        for (int m = 0; m < 4; m++) {
            int sw = ((m * 4 + quad) & 3) << 3;
            #pragma unroll
            for (int r = 0; r < 4; r++)
                sM[(m * 16 + quad * 4 + r) * M_STRIDE + ((nt * 16 + lc) ^ sw)] = f2bf(silu_f(acc[m][r]));
        }
    }
    __syncthreads();

    // ---- phase 5: m -> global + GEMM3 ----
    {
        int row = t >> 2, c0 = (t & 3) * 16;
        short8 v0 = *(const short8*)(sM + row * M_STRIDE + swz(row, c0));
        short8 v1 = *(const short8*)(sM + row * M_STRIDE + swz(row, c0 + 8));
        short* mg = (short*)m_edge + (size_t)(k0 + row) * FH + c0;
        *(short8*)(mg) = v0;
        *(short8*)(mg + 8) = v1;
    }
    {
        short8 ag[4][2];
        #pragma unroll
        for (int m = 0; m < 4; m++)
            #pragma unroll
            for (int kt = 0; kt < 2; kt++) {
                int row = m * 16 + lc;
                ag[m][kt] = *(const short8*)(sM + row * M_STRIDE + swz(row, kt * 32 + quad * 8));
            }
        float cwpart[4][4];
        #pragma unroll
        for (int m = 0; m < 4; m++)
            #pragma unroll
            for (int r = 0; r < 4; r++) cwpart[m][r] = 0.f;
        for (int nt = wid; nt < 16; nt += 4) {
            float bias = cb1[nt * 16 + lc];
            float4v acc[4];
            #pragma unroll
            for (int m = 0; m < 4; m++) acc[m] = (float4v){bias, bias, bias, bias};
            #pragma unroll
            for (int kt = 0; kt < 2; kt++) {
                short8 bh = ((const short8*)(cW1h + (size_t)(nt * 2 + kt) * 512))[lane];
                short8 bl = ((const short8*)(cW1l + (size_t)(nt * 2 + kt) * 512))[lane];
                #pragma unroll
                for (int m = 0; m < 4; m++) {
                    acc[m] = __builtin_amdgcn_mfma_f32_16x16x32_bf16(ag[m][kt], bh, acc[m], 0, 0, 0);
                    acc[m] = __builtin_amdgcn_mfma_f32_16x16x32_bf16(ag[m][kt], bl, acc[m], 0, 0, 0);
                }
            }
            float wv = cW2[nt * 16 + lc];
            #pragma unroll
            for (int m = 0; m < 4; m++)
                #pragma unroll
                for (int r = 0; r < 4; r++)
                    cwpart[m][r] += silu_f(acc[m][r]) * wv;
        }
        #pragma unroll
        for (int m = 0; m < 4; m++)
            #pragma unroll
            for (int r = 0; r < 4; r++) {
                float p = cwpart[m][r];
                p += __shfl_xor(p, 1);
                p += __shfl_xor(p, 2);
                p += __shfl_xor(p, 4);
                p += __shfl_xor(p, 8);
                if (lc == 0) cwbuf[wid * 64 + m * 16 + quad * 4 + r] = p;
            }
    }
    __syncthreads();

    if (t < 64) {
        float cw = cb2[0] + cwbuf[t] + cwbuf[64 + t] + cwbuf[128 + t] + cwbuf[192 + t];
        float* o = cwrel + (size_t)(k0 + t) * 3;
        o[0] = cw * sRel[t * 3 + 0];
        o[1] = cw * sRel[t * 3 + 1];
        o[2] = cw * sRel[t * 3 + 2];
    }
}

// ---------------- fused aggregation + node MLP ----------------
#define HS 136
__global__ __launch_bounds__(256, 2) void agg_node(
    const int* __restrict__ off, const int* __restrict__ deg,
    const __hip_bfloat16* __restrict__ m_edge, const float* __restrict__ cwrel,
    const float* __restrict__ coors_in, float* __restrict__ coors_out,
    float* __restrict__ feats, __hip_bfloat16* __restrict__ featsb,
    const short* __restrict__ W1h, const short* __restrict__ W1l, const float* __restrict__ b1,
    const short* __restrict__ W2h, const short* __restrict__ W2l, const float* __restrict__ b2)
{
    __shared__ short sh[64 * HS];   // h = [featsb | agg(m)]
    __shared__ short sg[64 * HS];   // silu(h@W1+b1), swizzled
    int t = threadIdx.x, lane = t & 63, wid = t >> 6, quad = lane >> 4, lc = lane & 15;
    int n0 = blockIdx.x * 64;

    // feats -> sh cols [0,64)
    {
        int row = t >> 2, sub = t & 3;
        const short8* fp = (const short8*)((const short*)featsb + (size_t)(n0 + row) * FH);
        *(short8*)(sh + row * HS + sub * 16) = fp[sub * 2];
        *(short8*)(sh + row * HS + sub * 16 + 8) = fp[sub * 2 + 1];
    }
    // aggregate m + coors: wave w owns rows [w*16, w*16+16)
    for (int nn = 0; nn < 16; nn++) {
        int row = wid * 16 + nn;
        int n = n0 + row;
        float sum = 0.f, cv = 0.f;
        if (n < NN) {
            int s = off[n], e = s + deg[n];
            for (int k = s; k < e; k++) {
                sum += bf2f(((const short*)m_edge)[(size_t)k * FH + lane]);
                if (lane < 3) cv += cwrel[(size_t)k * 3 + lane];
            }
            if (lane < 3) coors_out[n * 3 + lane] = coors_in[n * 3 + lane] + cv;
        }
        sh[row * HS + 64 + lane] = f2bf(sum);
    }
    __syncthreads();

    short8 af[4][4];
    #pragma unroll
    for (int m = 0; m < 4; m++)
        #pragma unroll
        for (int kt = 0; kt < 4; kt++)
            af[m][kt] = *(const short8*)(sh + (m * 16 + lc) * HS + kt * 32 + quad * 8);
    for (int nt = wid; nt < 8; nt += 4) {
        float bias = b1[nt * 16 + lc];
        float4v acc[4];
        #pragma unroll
        for (int m = 0; m < 4; m++) acc[m] = (float4v){bias, bias, bias, bias};
        #pragma unroll
        for (int kt = 0; kt < 4; kt++) {
            short8 bh = ((const short8*)(W1h + (size_t)(nt * 4 + kt) * 512))[lane];
            short8 bl = ((const short8*)(W1l + (size_t)(nt * 4 + kt) * 512))[lane];
            #pragma unroll
            for (int m = 0; m < 4; m++) {
                acc[m] = __builtin_amdgcn_mfma_f32_16x16x32_bf16(af[m][kt], bh, acc[m], 0, 0, 0);
                acc[m] = __builtin_amdgcn_mfma_f32_16x16x32_bf16(af[m][kt], bl, acc[m], 0, 0, 0);
            }
        }
        #pragma unroll
        for (int m = 0; m < 4; m++) {
            int sw = ((m * 4 + quad) & 3) << 3;
            #pragma unroll
            for (int r = 0; r < 4; r++)
                sg[(m * 16 + quad * 4 + r) * HS + ((nt * 16 + lc) ^ sw)] = f2bf(silu_f(acc[m][r]));
        }
    }
    __syncthreads();

    {
        int nt = wid;
        float bias = b2[nt * 16 + lc];
        float4v acc[4];
        #pragma unroll
        for (int m = 0; m < 4; m++) acc[m] = (float4v){bias, bias, bias, bias};
        #pragma unroll
        for (int kt = 0; kt < 4; kt++) {
            short8 bh = ((const short8*)(W2h + (size_t)(nt * 4 + kt) * 512))[lane];
            short8 bl = ((const short8*)(W2l + (size_t)(nt * 4 + kt) * 512))[lane];
            #pragma unroll
            for (int m = 0; m < 4; m++) {
                int row = m * 16 + lc;
                short8 a = *(const short8*)(sg + row * HS + swz(row, kt * 32 + quad * 8));
                acc[m] = __builtin_amdgcn_mfma_f32_16x16x32_bf16(a, bh, acc[m], 0, 0, 0);
                acc[m] = __builtin_amdgcn_mfma_f32_16x16x32_bf16(a, bl, acc[m], 0, 0, 0);
            }
        }
        #pragma unroll
        for (int m = 0; m < 4; m++)
            #pragma unroll
            for (int r = 0; r < 4; r++) {
                int row = m * 16 + quad * 4 + r;
                size_t idx = (size_t)(n0 + row) * FH + nt * 16 + lc;
                float nv = feats[idx] + acc[m][r];   // residual in fp32
                feats[idx] = nv;
                ((short*)featsb)[idx] = f2bf(nv);
            }
    }
}

__global__ void final_kernel(const float* __restrict__ feats, const float* __restrict__ linW,
                             const float* __restrict__ linb, float* __restrict__ out) {
    int t = blockIdx.x * 256 + threadIdx.x;
    int n = t >> 6;
    int lane = threadIdx.x & 63;
    if (n >= NN) return;
    float v = feats[(size_t)n * FH + lane] * linW[lane];
    #pragma unroll
    for (int off = 32; off > 0; off >>= 1) v += __shfl_down(v, off);
    if (lane == 0) out[n] = v + linb[0];
}

extern "C" void kernel_launch(void* const* d_in, const int* in_sizes, int n_in,
                              void* d_out, int out_size, void* d_ws, size_t ws_size,
                              hipStream_t stream) {
    const float* x      = (const float*)d_in[0];
    const float* pos    = (const float*)d_in[1];
    const int*   ei     = (const int*)d_in[2];
    const float* eattr  = (const float*)d_in[3];
    const float* embedW = (const float*)d_in[4];
    const float* embedb = (const float*)d_in[5];
    const float* eW1    = (const float*)d_in[6];
    const float* eb1    = (const float*)d_in[7];
    const float* eW2    = (const float*)d_in[8];
    const float* eb2    = (const float*)d_in[9];
    const float* cW1    = (const float*)d_in[10];
    const float* cb1    = (const float*)d_in[11];
    const float* cW2    = (const float*)d_in[12];
    const float* cb2    = (const float*)d_in[13];
    const float* nW1    = (const float*)d_in[14];
    const float* nb1    = (const float*)d_in[15];
    const float* nW2    = (const float*)d_in[16];
    const float* nb2    = (const float*)d_in[17];
    const float* linW   = (const float*)d_in[18];
    const float* linb   = (const float*)d_in[19];
    float* out = (float*)d_out;

    char* wp = (char*)d_ws;
    auto alloc = [&](size_t bytes) { void* p = wp; wp += (bytes + 255) & ~(size_t)255; return p; };

    const int W1F_L  = 17 * 5 * 512;
    const int W2F_L  = 4 * 9 * 512;
    const int CW1F_L = 16 * 2 * 512;
    const int NW1F_L = 8 * 4 * 512;
    const int NW2F_L = 4 * 4 * 512;

    float* feats  = (float*)alloc((size_t)NNP * FH * 4);
    __hip_bfloat16* featsb = (__hip_bfloat16*)alloc((size_t)NNP * FH * 2);
    float* cA     = (float*)alloc((size_t)NN * 3 * 4);
    float* cB     = (float*)alloc((size_t)NN * 3 * 4);
    short* W1fh   = (short*)alloc((size_t)3 * W1F_L * 2);
    short* W1fl   = (short*)alloc((size_t)3 * W1F_L * 2);
    short* W2fh   = (short*)alloc((size_t)3 * W2F_L * 2);
    short* W2fl   = (short*)alloc((size_t)3 * W2F_L * 2);
    short* cW1fh  = (short*)alloc((size_t)3 * CW1F_L * 2);
    short* cW1fl  = (short*)alloc((size_t)3 * CW1F_L * 2);
    short* nW1fh  = (short*)alloc((size_t)3 * NW1F_L * 2);
    short* nW1fl  = (short*)alloc((size_t)3 * NW1F_L * 2);
    short* nW2fh  = (short*)alloc((size_t)3 * NW2F_L * 2);
    short* nW2fl  = (short*)alloc((size_t)3 * NW2F_L * 2);
    float* b1p    = (float*)alloc((size_t)3 * 272 * 4);
    int*   deg    = (int*)alloc((size_t)(NN + 1) * 4);   // deg[NN] = global cursor
    int*   off    = (int*)alloc((size_t)NN * 4);
    int*   cursor = (int*)alloc((size_t)NN * 4);
    int*   erow   = (int*)alloc((size_t)NE * 4);
    int*   ecol   = (int*)alloc((size_t)NE * 4);
    float* eattrp = (float*)alloc((size_t)NE * 4);
    __hip_bfloat16* m_edge = (__hip_bfloat16*)alloc((size_t)NE * FH * 2);
    float* cwrel  = (float*)alloc((size_t)NE * 3 * 4);
    int* gcount = deg + NN;

    prep_all<<<(309552 + 255) / 256, 256, 0, stream>>>(
        eW1, eW2, cW1, nW1, nW2, eb1,
        W1fh, W1fl, W2fh, W2fl, cW1fh, cW1fl, nW1fh, nW1fl, nW2fh, nW2fl, b1p);

    // CSR build: hist -> per-block scan + global cursor -> fill
    hipMemsetAsync(deg, 0, (size_t)(NN + 1) * 4, stream);
    hist_kernel<<<(NE + 255) / 256, 256, 0, stream>>>(ei, deg);
    alloc_kernel<<<(NN + 255) / 256, 256, 0, stream>>>(deg, off, cursor, gcount);
    fill_kernel<<<(NE + 255) / 256, 256, 0, stream>>>(ei, eattr, cursor, erow, ecol, eattrp);

    embed_kernel<<<(NN * FH + 255) / 256, 256, 0, stream>>>(x, embedW, embedb, pos, feats, featsb, cA);

    float* ccur = cA;
    float* cnext = cB;
    for (int l = 0; l < 3; l++) {
        edge_fused<<<NE / 64, 256, 0, stream>>>(
            erow, ecol, eattrp, featsb, ccur,
            W1fh + (size_t)l * W1F_L, W1fl + (size_t)l * W1F_L, b1p + l * 272,
            W2fh + (size_t)l * W2F_L, W2fl + (size_t)l * W2F_L, eb2 + l * 64,
            cW1fh + (size_t)l * CW1F_L, cW1fl + (size_t)l * CW1F_L, cb1 + l * 256,
            cW2 + l * 256, cb2 + l,
            m_edge, cwrel);
        agg_node<<<NNP / 64, 256, 0, stream>>>(
            off, deg, m_edge, cwrel, ccur, cnext, feats, featsb,
            nW1fh + (size_t)l * NW1F_L, nW1fl + (size_t)l * NW1F_L, nb1 + l * 128,
            nW2fh + (size_t)l * NW2F_L, nW2fl + (size_t)l * NW2F_L, nb2 + l * 64);
        float* tmp = ccur; ccur = cnext; cnext = tmp;
    }
    final_kernel<<<(NN * FH) / 256, 256, 0, stream>>>(feats, linW, linb, out);
}

// Round 9
// 831.699 us; speedup vs baseline: 13.6568x; 1.0115x over previous
//
#include <hip/hip_runtime.h>
#include <hip/hip_bf16.h>

#define NN 50000
#define NNP 50048   // padded to 64-node blocks
#define NE 400000
#define FH 64

typedef __attribute__((ext_vector_type(8))) short short8;
typedef __attribute__((ext_vector_type(4))) float float4v;

__device__ __forceinline__ float silu_f(float x) {
    return x * __builtin_amdgcn_rcpf(1.0f + __expf(-x));
}
__device__ __forceinline__ short f2bf(float f) {
    __hip_bfloat16 h = __float2bfloat16(f);
    return *(short*)&h;
}
__device__ __forceinline__ float bf2f(short s) {
    __hip_bfloat16 h = *(__hip_bfloat16*)&s;
    return __bfloat162float(h);
}

// ---------------- mega weight prep (hi/lo bf16 frag pairs) ----------------
__device__ __forceinline__ void frag_body(const float* __restrict__ src,
                                          short* __restrict__ hi, short* __restrict__ lo,
                                          int t, int K, int N, int KT, int dup,
                                          int perL, int srcL) {
    int l = t / perL, tt = t - l * perL;
    int j = tt & 7, lane = (tt >> 3) & 63, frag = tt >> 9;
    int nt = frag / KT, kt = frag - nt * KT;
    int k = kt * 32 + ((lane >> 4) << 3) + j;
    int n = nt * 16 + (lane & 15);
    if (k == dup) k = dup - 1;
    float v = (k < K && n < N) ? src[(size_t)l * srcL + k * N + n] : 0.f;
    short h = f2bf(v);
    hi[t] = h;
    lo[t] = f2bf(v - bf2f(h));
}

__global__ void prep_all(const float* __restrict__ eW1, const float* __restrict__ eW2,
                         const float* __restrict__ cW1, const float* __restrict__ nW1,
                         const float* __restrict__ nW2, const float* __restrict__ eb1,
                         short* W1fh, short* W1fl, short* W2fh, short* W2fl,
                         short* cW1fh, short* cW1fl, short* nW1fh, short* nW1fl,
                         short* nW2fh, short* nW2fl, float* b1p) {
    int t = blockIdx.x * 256 + threadIdx.x;
    if (t < 130560) { frag_body(eW1, W1fh, W1fl, t, 131, 260, 5, 130, 43520, 33800); return; }
    t -= 130560;
    if (t < 55296) { frag_body(eW2, W2fh, W2fl, t, 260, 64, 9, -1, 18432, 16640); return; }
    t -= 55296;
    if (t < 49152) { frag_body(cW1, cW1fh, cW1fl, t, 64, 256, 2, -1, 16384, 16384); return; }
    t -= 49152;
    if (t < 49152) { frag_body(nW1, nW1fh, nW1fl, t, 128, 128, 4, -1, 16384, 16384); return; }
    t -= 49152;
    if (t < 24576) { frag_body(nW2, nW2fh, nW2fl, t, 128, 64, 4, -1, 8192, 8192); return; }
    t -= 24576;
    if (t < 816) { int l = t / 272, c = t - l * 272; b1p[t] = (c < 260) ? eb1[l * 260 + c] : 0.f; }
}

__global__ void embed_kernel(const float* __restrict__ x, const float* __restrict__ W,
                             const float* __restrict__ b, const float* __restrict__ pos,
                             float* __restrict__ feats, __hip_bfloat16* __restrict__ featsb,
                             float* __restrict__ cA) {
    int t = blockIdx.x * 256 + threadIdx.x;
    if (t >= NN * FH) return;
    int n = t >> 6, hcol = t & 63;
    float acc = b[hcol];
    #pragma unroll
    for (int k = 0; k < 8; k++) acc += x[n * 8 + k] * W[k * FH + hcol];
    feats[t] = acc;
    ((short*)featsb)[t] = f2bf(acc);
    if (hcol < 3) cA[n * 3 + hcol] = pos[n * 3 + hcol];
}

// ---------------- CSR build (block scan + global cursor) ----------------
__global__ void hist_kernel(const int* __restrict__ ei, int* __restrict__ deg) {
    int e = blockIdx.x * 256 + threadIdx.x;
    if (e >= NE) return;
    atomicAdd(&deg[ei[e]], 1);
}

__global__ void alloc_kernel(const int* __restrict__ deg, int* __restrict__ off,
                             int* __restrict__ cursor, int* __restrict__ gcount) {
    __shared__ int s[256];
    __shared__ int base;
    int t = threadIdx.x, n = blockIdx.x * 256 + t;
    int d = (n < NN) ? deg[n] : 0;
    s[t] = d;
    __syncthreads();
    for (int st = 1; st < 256; st <<= 1) {
        int v = (t >= st) ? s[t - st] : 0;
        __syncthreads();
        s[t] += v;
        __syncthreads();
    }
    if (t == 255) base = atomicAdd(gcount, s[255]);
    __syncthreads();
    if (n < NN) { int o = base + s[t] - d; off[n] = o; cursor[n] = o; }
}

__global__ void fill_kernel(const int* __restrict__ ei, const float* __restrict__ eattr,
                            int* __restrict__ cursor, int* __restrict__ erow,
                            int* __restrict__ ecol, float* __restrict__ eattrp) {
    int e = blockIdx.x * 256 + threadIdx.x;
    if (e >= NE) return;
    int r = ei[e];
    int p = atomicAdd(&cursor[r], 1);
    erow[p] = r;
    ecol[p] = ei[NE + e];
    eattrp[p] = eattr[e];
}

// ---------------- fused MFMA edge pipeline ----------------
#define SE_STRIDE 168   // shorts
#define H1_STRIDE 296
#define M_STRIDE  72

__global__ __launch_bounds__(256, 3) void edge_fused(
    const int* __restrict__ erow, const int* __restrict__ ecol,
    const float* __restrict__ eattrp,
    const __hip_bfloat16* __restrict__ featsb, const float* __restrict__ coors,
    const short* __restrict__ W1h, const short* __restrict__ W1l, const float* __restrict__ b1p,
    const short* __restrict__ W2h, const short* __restrict__ W2l, const float* __restrict__ b2,
    const short* __restrict__ cW1h, const short* __restrict__ cW1l, const float* __restrict__ cb1,
    const float* __restrict__ cW2, const float* __restrict__ cb2,
    __hip_bfloat16* __restrict__ m_edge, float* __restrict__ cwrel)
{
    __shared__ char smem[48896];
    short* sE   = (short*)smem;               // [0,21504)
    short* sH1  = (short*)smem;               // [0,37888) overlays sE
    short* sM   = (short*)(smem + 37888);     // [37888,47104)
    float* sRel = (float*)(smem + 47104);
    float* cwbuf = (float*)(smem + 47872);

    int t = threadIdx.x;
    int k0 = blockIdx.x * 64;
    int lane = t & 63, wid = t >> 6, quad = lane >> 4, lc = lane & 15;

    // ---- phase 1: gather e_in ----
    {
        int el = t >> 2, sub = t & 3, k = k0 + el;
        int rI = erow[k], cI = ecol[k];
        const short8* fr = (const short8*)((const short*)featsb + (size_t)rI * FH);
        const short8* fc = (const short8*)((const short*)featsb + (size_t)cI * FH);
        short* er = sE + el * SE_STRIDE;
        *(short8*)(er + sub * 16) = fr[sub * 2];
        *(short8*)(er + sub * 16 + 8) = fr[sub * 2 + 1];
        *(short8*)(er + 64 + sub * 16) = fc[sub * 2];
        *(short8*)(er + 64 + sub * 16 + 8) = fc[sub * 2 + 1];
        #pragma unroll
        for (int i = 0; i < 10; i++) er[128 + sub * 10 + i] = 0;
        if (sub == 0) {
            float rx = coors[rI * 3 + 0] - coors[cI * 3 + 0];
            float ry = coors[rI * 3 + 1] - coors[cI * 3 + 1];
            float rz = coors[rI * 3 + 2] - coors[cI * 3 + 2];
            float dist = rx * rx + ry * ry + rz * rz;
            short dh = f2bf(dist);
            er[128] = f2bf(eattrp[k]);
            er[129] = dh;
            er[130] = f2bf(dist - bf2f(dh));   // dist hi/lo columns (W1 row 130 = dup of 129)
            sRel[el * 3 + 0] = rx; sRel[el * 3 + 1] = ry; sRel[el * 3 + 2] = rz;
        }
    }
    __syncthreads();

    // ---- phase 2: A fragments to registers, fence before overlay ----
    short8 af[4][5];
    #pragma unroll
    for (int m = 0; m < 4; m++)
        #pragma unroll
        for (int kt = 0; kt < 5; kt++)
            af[m][kt] = *(const short8*)(sE + (m * 16 + lc) * SE_STRIDE + kt * 32 + quad * 8);
    __syncthreads();

    // ---- phase 3: GEMM1 e_in[64x160] @ (W1h+W1l)[160x272] -> silu -> sH1 ----
    {
        *(long long*)(sH1 + (t >> 2) * H1_STRIDE + 272 + (t & 3) * 4) = 0LL;
        // fixed-trip unrolled main loop: tiles 0..15 (wave w owns w, w+4, w+8, w+12)
        #pragma unroll
        for (int i = 0; i < 4; i++) {
            int nt = wid + i * 4;
            float bias = b1p[nt * 16 + lc];
            float4v acc[4];
            #pragma unroll
            for (int m = 0; m < 4; m++) acc[m] = (float4v){bias, bias, bias, bias};
            #pragma unroll
            for (int kt = 0; kt < 5; kt++) {
                short8 bh = ((const short8*)(W1h + (size_t)(nt * 5 + kt) * 512))[lane];
                short8 bl = ((const short8*)(W1l + (size_t)(nt * 5 + kt) * 512))[lane];
                #pragma unroll
                for (int m = 0; m < 4; m++) {
                    acc[m] = __builtin_amdgcn_mfma_f32_16x16x32_bf16(af[m][kt], bh, acc[m], 0, 0, 0);
                    acc[m] = __builtin_amdgcn_mfma_f32_16x16x32_bf16(af[m][kt], bl, acc[m], 0, 0, 0);
                }
            }
            #pragma unroll
            for (int m = 0; m < 4; m++)
                #pragma unroll
                for (int r = 0; r < 4; r++)
                    sH1[(m * 16 + quad * 4 + r) * H1_STRIDE + nt * 16 + lc] = f2bf(silu_f(acc[m][r]));
        }
        // tail tile nt=16 (wave 0 only)
        if (wid == 0) {
            const int nt = 16;
            float bias = b1p[nt * 16 + lc];
            float4v acc[4];
            #pragma unroll
            for (int m = 0; m < 4; m++) acc[m] = (float4v){bias, bias, bias, bias};
            #pragma unroll
            for (int kt = 0; kt < 5; kt++) {
                short8 bh = ((const short8*)(W1h + (size_t)(nt * 5 + kt) * 512))[lane];
                short8 bl = ((const short8*)(W1l + (size_t)(nt * 5 + kt) * 512))[lane];
                #pragma unroll
                for (int m = 0; m < 4; m++) {
                    acc[m] = __builtin_amdgcn_mfma_f32_16x16x32_bf16(af[m][kt], bh, acc[m], 0, 0, 0);
                    acc[m] = __builtin_amdgcn_mfma_f32_16x16x32_bf16(af[m][kt], bl, acc[m], 0, 0, 0);
                }
            }
            #pragma unroll
            for (int m = 0; m < 4; m++)
                #pragma unroll
                for (int r = 0; r < 4; r++)
                    sH1[(m * 16 + quad * 4 + r) * H1_STRIDE + nt * 16 + lc] = f2bf(silu_f(acc[m][r]));
        }
    }
    __syncthreads();

    // ---- phase 4: GEMM2 H1[64x288] @ (W2h+W2l)[288x64] -> silu -> sM ----
    {
        int nt = wid;
        float bias = b2[nt * 16 + lc];
        float4v acc[4];
        #pragma unroll
        for (int m = 0; m < 4; m++) acc[m] = (float4v){bias, bias, bias, bias};
        #pragma unroll
        for (int kt = 0; kt < 9; kt++) {
            short8 bh = ((const short8*)(W2h + (size_t)(nt * 9 + kt) * 512))[lane];
            short8 bl = ((const short8*)(W2l + (size_t)(nt * 9 + kt) * 512))[lane];
            #pragma unroll
            for (int m = 0; m < 4; m++) {
                short8 a = *(const short8*)(sH1 + (m * 16 + lc) * H1_STRIDE + kt * 32 + quad * 8);
                acc[m] = __builtin_amdgcn_mfma_f32_16x16x32_bf16(a, bh, acc[m], 0, 0, 0);
                acc[m] = __builtin_amdgcn_mfma_f32_16x16x32_bf16(a, bl, acc[m], 0, 0, 0);
            }
        }
        #pragma unroll
        for (int m = 0; m < 4; m++)
            #pragma unroll
            for (int r = 0; r < 4; r++)
                sM[(m * 16 + quad * 4 + r) * M_STRIDE + nt * 16 + lc] = f2bf(silu_f(acc[m][r]));
    }
    __syncthreads();

    // ---- phase 5: m -> global + GEMM3 (fixed-trip unrolled) ----
    {
        int row = t >> 2, c0 = (t & 3) * 16;
        short8 v0 = *(const short8*)(sM + row * M_STRIDE + c0);
        short8 v1 = *(const short8*)(sM + row * M_STRIDE + c0 + 8);
        short* mg = (short*)m_edge + (size_t)(k0 + row) * FH + c0;
        *(short8*)(mg) = v0;
        *(short8*)(mg + 8) = v1;
    }
    {
        short8 ag[4][2];
        #pragma unroll
        for (int m = 0; m < 4; m++)
            #pragma unroll
            for (int kt = 0; kt < 2; kt++)
                ag[m][kt] = *(const short8*)(sM + (m * 16 + lc) * M_STRIDE + kt * 32 + quad * 8);
        float cwpart[4][4];
        #pragma unroll
        for (int m = 0; m < 4; m++)
            #pragma unroll
            for (int r = 0; r < 4; r++) cwpart[m][r] = 0.f;
        #pragma unroll
        for (int i = 0; i < 4; i++) {
            int nt = wid + i * 4;
            float bias = cb1[nt * 16 + lc];
            float4v acc[4];
            #pragma unroll
            for (int m = 0; m < 4; m++) acc[m] = (float4v){bias, bias, bias, bias};
            #pragma unroll
            for (int kt = 0; kt < 2; kt++) {
                short8 bh = ((const short8*)(cW1h + (size_t)(nt * 2 + kt) * 512))[lane];
                short8 bl = ((const short8*)(cW1l + (size_t)(nt * 2 + kt) * 512))[lane];
                #pragma unroll
                for (int m = 0; m < 4; m++) {
                    acc[m] = __builtin_amdgcn_mfma_f32_16x16x32_bf16(ag[m][kt], bh, acc[m], 0, 0, 0);
                    acc[m] = __builtin_amdgcn_mfma_f32_16x16x32_bf16(ag[m][kt], bl, acc[m], 0, 0, 0);
                }
            }
            float wv = cW2[nt * 16 + lc];
            #pragma unroll
            for (int m = 0; m < 4; m++)
                #pragma unroll
                for (int r = 0; r < 4; r++)
                    cwpart[m][r] += silu_f(acc[m][r]) * wv;
        }
        #pragma unroll
        for (int m = 0; m < 4; m++)
            #pragma unroll
            for (int r = 0; r < 4; r++) {
                float p = cwpart[m][r];
                p += __shfl_xor(p, 1);
                p += __shfl_xor(p, 2);
                p += __shfl_xor(p, 4);
                p += __shfl_xor(p, 8);
                if (lc == 0) cwbuf[wid * 64 + m * 16 + quad * 4 + r] = p;
            }
    }
    __syncthreads();

    if (t < 64) {
        float cw = cb2[0] + cwbuf[t] + cwbuf[64 + t] + cwbuf[128 + t] + cwbuf[192 + t];
        float* o = cwrel + (size_t)(k0 + t) * 3;
        o[0] = cw * sRel[t * 3 + 0];
        o[1] = cw * sRel[t * 3 + 1];
        o[2] = cw * sRel[t * 3 + 2];
    }
}

// ---------------- fused aggregation + node MLP ----------------
#define HS 136
__global__ __launch_bounds__(256, 2) void agg_node(
    const int* __restrict__ off, const int* __restrict__ deg,
    const __hip_bfloat16* __restrict__ m_edge, const float* __restrict__ cwrel,
    const float* __restrict__ coors_in, float* __restrict__ coors_out,
    float* __restrict__ feats, __hip_bfloat16* __restrict__ featsb,
    const short* __restrict__ W1h, const short* __restrict__ W1l, const float* __restrict__ b1,
    const short* __restrict__ W2h, const short* __restrict__ W2l, const float* __restrict__ b2)
{
    __shared__ short sh[64 * HS];   // h = [featsb | agg(m)]
    __shared__ short sg[64 * HS];   // silu(h@W1+b1)
    int t = threadIdx.x, lane = t & 63, wid = t >> 6, quad = lane >> 4, lc = lane & 15;
    int n0 = blockIdx.x * 64;

    {
        int row = t >> 2, sub = t & 3;
        const short8* fp = (const short8*)((const short*)featsb + (size_t)(n0 + row) * FH);
        *(short8*)(sh + row * HS + sub * 16) = fp[sub * 2];
        *(short8*)(sh + row * HS + sub * 16 + 8) = fp[sub * 2 + 1];
    }
    for (int nn = 0; nn < 16; nn++) {
        int row = wid * 16 + nn;
        int n = n0 + row;
        float sum = 0.f, cv = 0.f;
        if (n < NN) {
            int s = off[n], e = s + deg[n];
            for (int k = s; k < e; k++) {
                sum += bf2f(((const short*)m_edge)[(size_t)k * FH + lane]);
                if (lane < 3) cv += cwrel[(size_t)k * 3 + lane];
            }
            if (lane < 3) coors_out[n * 3 + lane] = coors_in[n * 3 + lane] + cv;
        }
        sh[row * HS + 64 + lane] = f2bf(sum);
    }
    __syncthreads();

    short8 af[4][4];
    #pragma unroll
    for (int m = 0; m < 4; m++)
        #pragma unroll
        for (int kt = 0; kt < 4; kt++)
            af[m][kt] = *(const short8*)(sh + (m * 16 + lc) * HS + kt * 32 + quad * 8);
    #pragma unroll
    for (int i = 0; i < 2; i++) {
        int nt = wid + i * 4;
        float bias = b1[nt * 16 + lc];
        float4v acc[4];
        #pragma unroll
        for (int m = 0; m < 4; m++) acc[m] = (float4v){bias, bias, bias, bias};
        #pragma unroll
        for (int kt = 0; kt < 4; kt++) {
            short8 bh = ((const short8*)(W1h + (size_t)(nt * 4 + kt) * 512))[lane];
            short8 bl = ((const short8*)(W1l + (size_t)(nt * 4 + kt) * 512))[lane];
            #pragma unroll
            for (int m = 0; m < 4; m++) {
                acc[m] = __builtin_amdgcn_mfma_f32_16x16x32_bf16(af[m][kt], bh, acc[m], 0, 0, 0);
                acc[m] = __builtin_amdgcn_mfma_f32_16x16x32_bf16(af[m][kt], bl, acc[m], 0, 0, 0);
            }
        }
        #pragma unroll
        for (int m = 0; m < 4; m++)
            #pragma unroll
            for (int r = 0; r < 4; r++)
                sg[(m * 16 + quad * 4 + r) * HS + nt * 16 + lc] = f2bf(silu_f(acc[m][r]));
    }
    __syncthreads();

    {
        int nt = wid;
        float bias = b2[nt * 16 + lc];
        float4v acc[4];
        #pragma unroll
        for (int m = 0; m < 4; m++) acc[m] = (float4v){bias, bias, bias, bias};
        #pragma unroll
        for (int kt = 0; kt < 4; kt++) {
            short8 bh = ((const short8*)(W2h + (size_t)(nt * 4 + kt) * 512))[lane];
            short8 bl = ((const short8*)(W2l + (size_t)(nt * 4 + kt) * 512))[lane];
            #pragma unroll
            for (int m = 0; m < 4; m++) {
                short8 a = *(const short8*)(sg + (m * 16 + lc) * HS + kt * 32 + quad * 8);
                acc[m] = __builtin_amdgcn_mfma_f32_16x16x32_bf16(a, bh, acc[m], 0, 0, 0);
                acc[m] = __builtin_amdgcn_mfma_f32_16x16x32_bf16(a, bl, acc[m], 0, 0, 0);
            }
        }
        #pragma unroll
        for (int m = 0; m < 4; m++)
            #pragma unroll
            for (int r = 0; r < 4; r++) {
                int row = m * 16 + quad * 4 + r;
                size_t idx = (size_t)(n0 + row) * FH + nt * 16 + lc;
                float nv = feats[idx] + acc[m][r];   // residual in fp32
                feats[idx] = nv;
                ((short*)featsb)[idx] = f2bf(nv);
            }
    }
}

__global__ void final_kernel(const float* __restrict__ feats, const float* __restrict__ linW,
                             const float* __restrict__ linb, float* __restrict__ out) {
    int t = blockIdx.x * 256 + threadIdx.x;
    int n = t >> 6;
    int lane = threadIdx.x & 63;
    if (n >= NN) return;
    float v = feats[(size_t)n * FH + lane] * linW[lane];
    #pragma unroll
    for (int off = 32; off > 0; off >>= 1) v += __shfl_down(v, off);
    if (lane == 0) out[n] = v + linb[0];
}

extern "C" void kernel_launch(void* const* d_in, const int* in_sizes, int n_in,
                              void* d_out, int out_size, void* d_ws, size_t ws_size,
                              hipStream_t stream) {
    const float* x      = (const float*)d_in[0];
    const float* pos    = (const float*)d_in[1];
    const int*   ei     = (const int*)d_in[2];
    const float* eattr  = (const float*)d_in[3];
    const float* embedW = (const float*)d_in[4];
    const float* embedb = (const float*)d_in[5];
    const float* eW1    = (const float*)d_in[6];
    const float* eb1    = (const float*)d_in[7];
    const float* eW2    = (const float*)d_in[8];
    const float* eb2    = (const float*)d_in[9];
    const float* cW1    = (const float*)d_in[10];
    const float* cb1    = (const float*)d_in[11];
    const float* cW2    = (const float*)d_in[12];
    const float* cb2    = (const float*)d_in[13];
    const float* nW1    = (const float*)d_in[14];
    const float* nb1    = (const float*)d_in[15];
    const float* nW2    = (const float*)d_in[16];
    const float* nb2    = (const float*)d_in[17];
    const float* linW   = (const float*)d_in[18];
    const float* linb   = (const float*)d_in[19];
    float* out = (float*)d_out;

    char* wp = (char*)d_ws;
    auto alloc = [&](size_t bytes) { void* p = wp; wp += (bytes + 255) & ~(size_t)255; return p; };

    const int W1F_L  = 17 * 5 * 512;
    const int W2F_L  = 4 * 9 * 512;
    const int CW1F_L = 16 * 2 * 512;
    const int NW1F_L = 8 * 4 * 512;
    const int NW2F_L = 4 * 4 * 512;

    float* feats  = (float*)alloc((size_t)NNP * FH * 4);
    __hip_bfloat16* featsb = (__hip_bfloat16*)alloc((size_t)NNP * FH * 2);
    float* cA     = (float*)alloc((size_t)NN * 3 * 4);
    float* cB     = (float*)alloc((size_t)NN * 3 * 4);
    short* W1fh   = (short*)alloc((size_t)3 * W1F_L * 2);
    short* W1fl   = (short*)alloc((size_t)3 * W1F_L * 2);
    short* W2fh   = (short*)alloc((size_t)3 * W2F_L * 2);
    short* W2fl   = (short*)alloc((size_t)3 * W2F_L * 2);
    short* cW1fh  = (short*)alloc((size_t)3 * CW1F_L * 2);
    short* cW1fl  = (short*)alloc((size_t)3 * CW1F_L * 2);
    short* nW1fh  = (short*)alloc((size_t)3 * NW1F_L * 2);
    short* nW1fl  = (short*)alloc((size_t)3 * NW1F_L * 2);
    short* nW2fh  = (short*)alloc((size_t)3 * NW2F_L * 2);
    short* nW2fl  = (short*)alloc((size_t)3 * NW2F_L * 2);
    float* b1p    = (float*)alloc((size_t)3 * 272 * 4);
    int*   deg    = (int*)alloc((size_t)(NN + 1) * 4);   // deg[NN] = global cursor
    int*   off    = (int*)alloc((size_t)NN * 4);
    int*   cursor = (int*)alloc((size_t)NN * 4);
    int*   erow   = (int*)alloc((size_t)NE * 4);
    int*   ecol   = (int*)alloc((size_t)NE * 4);
    float* eattrp = (float*)alloc((size_t)NE * 4);
    __hip_bfloat16* m_edge = (__hip_bfloat16*)alloc((size_t)NE * FH * 2);
    float* cwrel  = (float*)alloc((size_t)NE * 3 * 4);
    int* gcount = deg + NN;

    prep_all<<<(309552 + 255) / 256, 256, 0, stream>>>(
        eW1, eW2, cW1, nW1, nW2, eb1,
        W1fh, W1fl, W2fh, W2fl, cW1fh, cW1fl, nW1fh, nW1fl, nW2fh, nW2fl, b1p);

    hipMemsetAsync(deg, 0, (size_t)(NN + 1) * 4, stream);
    hist_kernel<<<(NE + 255) / 256, 256, 0, stream>>>(ei, deg);
    alloc_kernel<<<(NN + 255) / 256, 256, 0, stream>>>(deg, off, cursor, gcount);
    fill_kernel<<<(NE + 255) / 256, 256, 0, stream>>>(ei, eattr, cursor, erow, ecol, eattrp);

    embed_kernel<<<(NN * FH + 255) / 256, 256, 0, stream>>>(x, embedW, embedb, pos, feats, featsb, cA);

    float* ccur = cA;
    float* cnext = cB;
    for (int l = 0; l < 3; l++) {
        edge_fused<<<NE / 64, 256, 0, stream>>>(
            erow, ecol, eattrp, featsb, ccur,
            W1fh + (size_t)l * W1F_L, W1fl + (size_t)l * W1F_L, b1p + l * 272,
            W2fh + (size_t)l * W2F_L, W2fl + (size_t)l * W2F_L, eb2 + l * 64,
            cW1fh + (size_t)l * CW1F_L, cW1fl + (size_t)l * CW1F_L, cb1 + l * 256,
            cW2 + l * 256, cb2 + l,
            m_edge, cwrel);
        agg_node<<<NNP / 64, 256, 0, stream>>>(
            off, deg, m_edge, cwrel, ccur, cnext, feats, featsb,
            nW1fh + (size_t)l * NW1F_L, nW1fl + (size_t)l * NW1F_L, nb1 + l * 128,
            nW2fh + (size_t)l * NW2F_L, nW2fl + (size_t)l * NW2F_L, nb2 + l * 64);
        float* tmp = ccur; ccur = cnext; cnext = tmp;
    }
    final_kernel<<<(NN * FH) / 256, 256, 0, stream>>>(feats, linW, linb, out);
}

// Round 10
// 728.638 us; speedup vs baseline: 15.5884x; 1.1414x over previous
//
#include <hip/hip_runtime.h>
#include <hip/hip_bf16.h>

#define NN 50000
#define NNP 50048   // padded to 64-node blocks
#define NE 400000
#define FH 64

typedef __attribute__((ext_vector_type(8))) short short8;
typedef __attribute__((ext_vector_type(8))) _Float16 half8;
typedef __attribute__((ext_vector_type(4))) float float4v;

__device__ __forceinline__ float silu_f(float x) {
    return x * __builtin_amdgcn_rcpf(1.0f + __expf(-x));
}
__device__ __forceinline__ short f2h(float f) {
    _Float16 h = (_Float16)f;
    return *(short*)&h;
}
__device__ __forceinline__ float h2f(short s) {
    _Float16 h = *(_Float16*)&s;
    return (float)h;
}

// ---------------- mega weight prep (single fp16 frags) ----------------
// src float [L][K][N] -> fp16 frags, frag(nt,kt) at (nt*KT+kt)*512,
// element (lane,j) = W[kt*32+(lane>>4)*8+j][nt*16+(lane&15)], zero-padded.
__device__ __forceinline__ void frag_body(const float* __restrict__ src,
                                          short* __restrict__ dst,
                                          int t, int K, int N, int KT, int dup,
                                          int perL, int srcL) {
    int l = t / perL, tt = t - l * perL;
    int j = tt & 7, lane = (tt >> 3) & 63, frag = tt >> 9;
    int nt = frag / KT, kt = frag - nt * KT;
    int k = kt * 32 + ((lane >> 4) << 3) + j;
    int n = nt * 16 + (lane & 15);
    if (k == dup) k = dup - 1;
    float v = (k < K && n < N) ? src[(size_t)l * srcL + k * N + n] : 0.f;
    dst[t] = f2h(v);
}

__global__ void prep_all(const float* __restrict__ eW1, const float* __restrict__ eW2,
                         const float* __restrict__ cW1, const float* __restrict__ nW1,
                         const float* __restrict__ nW2, const float* __restrict__ eb1,
                         short* W1f, short* W2f, short* cW1f, short* nW1f,
                         short* nW2f, float* b1p) {
    int t = blockIdx.x * 256 + threadIdx.x;
    if (t < 130560) { frag_body(eW1, W1f, t, 131, 260, 5, 130, 43520, 33800); return; }
    t -= 130560;
    if (t < 55296) { frag_body(eW2, W2f, t, 260, 64, 9, -1, 18432, 16640); return; }
    t -= 55296;
    if (t < 49152) { frag_body(cW1, cW1f, t, 64, 256, 2, -1, 16384, 16384); return; }
    t -= 49152;
    if (t < 49152) { frag_body(nW1, nW1f, t, 128, 128, 4, -1, 16384, 16384); return; }
    t -= 49152;
    if (t < 24576) { frag_body(nW2, nW2f, t, 128, 64, 4, -1, 8192, 8192); return; }
    t -= 24576;
    if (t < 816) { int l = t / 272, c = t - l * 272; b1p[t] = (c < 260) ? eb1[l * 260 + c] : 0.f; }
}

__global__ void embed_kernel(const float* __restrict__ x, const float* __restrict__ W,
                             const float* __restrict__ b, const float* __restrict__ pos,
                             float* __restrict__ feats, short* __restrict__ featsh,
                             float* __restrict__ cA) {
    int t = blockIdx.x * 256 + threadIdx.x;
    if (t >= NN * FH) return;
    int n = t >> 6, hcol = t & 63;
    float acc = b[hcol];
    #pragma unroll
    for (int k = 0; k < 8; k++) acc += x[n * 8 + k] * W[k * FH + hcol];
    feats[t] = acc;
    featsh[t] = f2h(acc);
    if (hcol < 3) cA[n * 3 + hcol] = pos[n * 3 + hcol];
}

// ---------------- CSR build (block scan + global cursor) ----------------
__global__ void hist_kernel(const int* __restrict__ ei, int* __restrict__ deg) {
    int e = blockIdx.x * 256 + threadIdx.x;
    if (e >= NE) return;
    atomicAdd(&deg[ei[e]], 1);
}

__global__ void alloc_kernel(const int* __restrict__ deg, int* __restrict__ off,
                             int* __restrict__ cursor, int* __restrict__ gcount) {
    __shared__ int s[256];
    __shared__ int base;
    int t = threadIdx.x, n = blockIdx.x * 256 + t;
    int d = (n < NN) ? deg[n] : 0;
    s[t] = d;
    __syncthreads();
    for (int st = 1; st < 256; st <<= 1) {
        int v = (t >= st) ? s[t - st] : 0;
        __syncthreads();
        s[t] += v;
        __syncthreads();
    }
    if (t == 255) base = atomicAdd(gcount, s[255]);
    __syncthreads();
    if (n < NN) { int o = base + s[t] - d; off[n] = o; cursor[n] = o; }
}

__global__ void fill_kernel(const int* __restrict__ ei, const float* __restrict__ eattr,
                            int* __restrict__ cursor, int* __restrict__ erow,
                            int* __restrict__ ecol, float* __restrict__ eattrp) {
    int e = blockIdx.x * 256 + threadIdx.x;
    if (e >= NE) return;
    int r = ei[e];
    int p = atomicAdd(&cursor[r], 1);
    erow[p] = r;
    ecol[p] = ei[NE + e];
    eattrp[p] = eattr[e];
}

// ---------------- fused MFMA edge pipeline (fp16) ----------------
#define SE_STRIDE 168   // shorts
#define H1_STRIDE 296
#define M_STRIDE  72

__global__ __launch_bounds__(256, 3) void edge_fused(
    const int* __restrict__ erow, const int* __restrict__ ecol,
    const float* __restrict__ eattrp,
    const short* __restrict__ featsh, const float* __restrict__ coors,
    const short* __restrict__ W1f, const float* __restrict__ b1p,
    const short* __restrict__ W2f, const float* __restrict__ b2,
    const short* __restrict__ cW1f, const float* __restrict__ cb1,
    const float* __restrict__ cW2, const float* __restrict__ cb2,
    short* __restrict__ m_edge, float* __restrict__ cwrel)
{
    __shared__ char smem[48896];
    short* sE   = (short*)smem;               // [0,21504)
    short* sH1  = (short*)smem;               // [0,37888) overlays sE
    short* sM   = (short*)(smem + 37888);     // [37888,47104)
    float* sRel = (float*)(smem + 47104);
    float* cwbuf = (float*)(smem + 47872);

    int t = threadIdx.x;
    int k0 = blockIdx.x * 64;
    int lane = t & 63, wid = t >> 6, quad = lane >> 4, lc = lane & 15;

    // ---- phase 1: gather e_in ----
    {
        int el = t >> 2, sub = t & 3, k = k0 + el;
        int rI = erow[k], cI = ecol[k];
        const short8* fr = (const short8*)(featsh + (size_t)rI * FH);
        const short8* fc = (const short8*)(featsh + (size_t)cI * FH);
        short* er = sE + el * SE_STRIDE;
        *(short8*)(er + sub * 16) = fr[sub * 2];
        *(short8*)(er + sub * 16 + 8) = fr[sub * 2 + 1];
        *(short8*)(er + 64 + sub * 16) = fc[sub * 2];
        *(short8*)(er + 64 + sub * 16 + 8) = fc[sub * 2 + 1];
        #pragma unroll
        for (int i = 0; i < 10; i++) er[128 + sub * 10 + i] = 0;
        if (sub == 0) {
            float rx = coors[rI * 3 + 0] - coors[cI * 3 + 0];
            float ry = coors[rI * 3 + 1] - coors[cI * 3 + 1];
            float rz = coors[rI * 3 + 2] - coors[cI * 3 + 2];
            float dist = rx * rx + ry * ry + rz * rz;
            short dh = f2h(dist);
            er[128] = f2h(eattrp[k]);
            er[129] = dh;
            er[130] = f2h(dist - h2f(dh));   // dist hi/lo columns (W1 row 130 = dup of 129)
            sRel[el * 3 + 0] = rx; sRel[el * 3 + 1] = ry; sRel[el * 3 + 2] = rz;
        }
    }
    __syncthreads();

    // ---- phase 2: A fragments to registers, fence before overlay ----
    half8 af[4][5];
    #pragma unroll
    for (int m = 0; m < 4; m++)
        #pragma unroll
        for (int kt = 0; kt < 5; kt++)
            af[m][kt] = *(const half8*)(sE + (m * 16 + lc) * SE_STRIDE + kt * 32 + quad * 8);
    __syncthreads();

    // ---- phase 3: GEMM1 e_in[64x160] @ W1[160x272] -> silu -> sH1 ----
    {
        *(long long*)(sH1 + (t >> 2) * H1_STRIDE + 272 + (t & 3) * 4) = 0LL;
        #pragma unroll
        for (int i = 0; i < 4; i++) {
            int nt = wid + i * 4;
            float bias = b1p[nt * 16 + lc];
            float4v acc[4];
            #pragma unroll
            for (int m = 0; m < 4; m++) acc[m] = (float4v){bias, bias, bias, bias};
            #pragma unroll
            for (int kt = 0; kt < 5; kt++) {
                half8 bh = ((const half8*)(W1f + (size_t)(nt * 5 + kt) * 512))[lane];
                #pragma unroll
                for (int m = 0; m < 4; m++)
                    acc[m] = __builtin_amdgcn_mfma_f32_16x16x32_f16(af[m][kt], bh, acc[m], 0, 0, 0);
            }
            #pragma unroll
            for (int m = 0; m < 4; m++)
                #pragma unroll
                for (int r = 0; r < 4; r++)
                    sH1[(m * 16 + quad * 4 + r) * H1_STRIDE + nt * 16 + lc] = f2h(silu_f(acc[m][r]));
        }
        if (wid == 0) {
            const int nt = 16;
            float bias = b1p[nt * 16 + lc];
            float4v acc[4];
            #pragma unroll
            for (int m = 0; m < 4; m++) acc[m] = (float4v){bias, bias, bias, bias};
            #pragma unroll
            for (int kt = 0; kt < 5; kt++) {
                half8 bh = ((const half8*)(W1f + (size_t)(nt * 5 + kt) * 512))[lane];
                #pragma unroll
                for (int m = 0; m < 4; m++)
                    acc[m] = __builtin_amdgcn_mfma_f32_16x16x32_f16(af[m][kt], bh, acc[m], 0, 0, 0);
            }
            #pragma unroll
            for (int m = 0; m < 4; m++)
                #pragma unroll
                for (int r = 0; r < 4; r++)
                    sH1[(m * 16 + quad * 4 + r) * H1_STRIDE + nt * 16 + lc] = f2h(silu_f(acc[m][r]));
        }
    }
    __syncthreads();

    // ---- phase 4: GEMM2 H1[64x288] @ W2[288x64] -> silu -> sM ----
    {
        int nt = wid;
        float bias = b2[nt * 16 + lc];
        float4v acc[4];
        #pragma unroll
        for (int m = 0; m < 4; m++) acc[m] = (float4v){bias, bias, bias, bias};
        #pragma unroll
        for (int kt = 0; kt < 9; kt++) {
            half8 bh = ((const half8*)(W2f + (size_t)(nt * 9 + kt) * 512))[lane];
            #pragma unroll
            for (int m = 0; m < 4; m++) {
                half8 a = *(const half8*)(sH1 + (m * 16 + lc) * H1_STRIDE + kt * 32 + quad * 8);
                acc[m] = __builtin_amdgcn_mfma_f32_16x16x32_f16(a, bh, acc[m], 0, 0, 0);
            }
        }
        #pragma unroll
        for (int m = 0; m < 4; m++)
            #pragma unroll
            for (int r = 0; r < 4; r++)
                sM[(m * 16 + quad * 4 + r) * M_STRIDE + nt * 16 + lc] = f2h(silu_f(acc[m][r]));
    }
    __syncthreads();

    // ---- phase 5: m -> global + GEMM3 ----
    {
        int row = t >> 2, c0 = (t & 3) * 16;
        short8 v0 = *(const short8*)(sM + row * M_STRIDE + c0);
        short8 v1 = *(const short8*)(sM + row * M_STRIDE + c0 + 8);
        short* mg = m_edge + (size_t)(k0 + row) * FH + c0;
        *(short8*)(mg) = v0;
        *(short8*)(mg + 8) = v1;
    }
    {
        half8 ag[4][2];
        #pragma unroll
        for (int m = 0; m < 4; m++)
            #pragma unroll
            for (int kt = 0; kt < 2; kt++)
                ag[m][kt] = *(const half8*)(sM + (m * 16 + lc) * M_STRIDE + kt * 32 + quad * 8);
        float cwpart[4][4];
        #pragma unroll
        for (int m = 0; m < 4; m++)
            #pragma unroll
            for (int r = 0; r < 4; r++) cwpart[m][r] = 0.f;
        #pragma unroll
        for (int i = 0; i < 4; i++) {
            int nt = wid + i * 4;
            float bias = cb1[nt * 16 + lc];
            float4v acc[4];
            #pragma unroll
            for (int m = 0; m < 4; m++) acc[m] = (float4v){bias, bias, bias, bias};
            #pragma unroll
            for (int kt = 0; kt < 2; kt++) {
                half8 bh = ((const half8*)(cW1f + (size_t)(nt * 2 + kt) * 512))[lane];
                #pragma unroll
                for (int m = 0; m < 4; m++)
                    acc[m] = __builtin_amdgcn_mfma_f32_16x16x32_f16(ag[m][kt], bh, acc[m], 0, 0, 0);
            }
            float wv = cW2[nt * 16 + lc];
            #pragma unroll
            for (int m = 0; m < 4; m++)
                #pragma unroll
                for (int r = 0; r < 4; r++)
                    cwpart[m][r] += silu_f(acc[m][r]) * wv;
        }
        #pragma unroll
        for (int m = 0; m < 4; m++)
            #pragma unroll
            for (int r = 0; r < 4; r++) {
                float p = cwpart[m][r];
                p += __shfl_xor(p, 1);
                p += __shfl_xor(p, 2);
                p += __shfl_xor(p, 4);
                p += __shfl_xor(p, 8);
                if (lc == 0) cwbuf[wid * 64 + m * 16 + quad * 4 + r] = p;
            }
    }
    __syncthreads();

    if (t < 64) {
        float cw = cb2[0] + cwbuf[t] + cwbuf[64 + t] + cwbuf[128 + t] + cwbuf[192 + t];
        float* o = cwrel + (size_t)(k0 + t) * 3;
        o[0] = cw * sRel[t * 3 + 0];
        o[1] = cw * sRel[t * 3 + 1];
        o[2] = cw * sRel[t * 3 + 2];
    }
}

// ---------------- fused aggregation + node MLP (fp16) ----------------
#define HS 136
__global__ __launch_bounds__(256, 2) void agg_node(
    const int* __restrict__ off, const int* __restrict__ deg,
    const short* __restrict__ m_edge, const float* __restrict__ cwrel,
    const float* __restrict__ coors_in, float* __restrict__ coors_out,
    float* __restrict__ feats, short* __restrict__ featsh,
    const short* __restrict__ W1f, const float* __restrict__ b1,
    const short* __restrict__ W2f, const float* __restrict__ b2)
{
    __shared__ short sh[64 * HS];   // h = [featsh | agg(m)]
    __shared__ short sg[64 * HS];   // silu(h@W1+b1)
    int t = threadIdx.x, lane = t & 63, wid = t >> 6, quad = lane >> 4, lc = lane & 15;
    int n0 = blockIdx.x * 64;

    {
        int row = t >> 2, sub = t & 3;
        const short8* fp = (const short8*)(featsh + (size_t)(n0 + row) * FH);
        *(short8*)(sh + row * HS + sub * 16) = fp[sub * 2];
        *(short8*)(sh + row * HS + sub * 16 + 8) = fp[sub * 2 + 1];
    }
    for (int nn = 0; nn < 16; nn++) {
        int row = wid * 16 + nn;
        int n = n0 + row;
        float sum = 0.f, cv = 0.f;
        if (n < NN) {
            int s = off[n], e = s + deg[n];
            for (int k = s; k < e; k++) {
                sum += h2f(m_edge[(size_t)k * FH + lane]);
                if (lane < 3) cv += cwrel[(size_t)k * 3 + lane];
            }
            if (lane < 3) coors_out[n * 3 + lane] = coors_in[n * 3 + lane] + cv;
        }
        sh[row * HS + 64 + lane] = f2h(sum);
    }
    __syncthreads();

    half8 af[4][4];
    #pragma unroll
    for (int m = 0; m < 4; m++)
        #pragma unroll
        for (int kt = 0; kt < 4; kt++)
            af[m][kt] = *(const half8*)(sh + (m * 16 + lc) * HS + kt * 32 + quad * 8);
    #pragma unroll
    for (int i = 0; i < 2; i++) {
        int nt = wid + i * 4;
        float bias = b1[nt * 16 + lc];
        float4v acc[4];
        #pragma unroll
        for (int m = 0; m < 4; m++) acc[m] = (float4v){bias, bias, bias, bias};
        #pragma unroll
        for (int kt = 0; kt < 4; kt++) {
            half8 bh = ((const half8*)(W1f + (size_t)(nt * 4 + kt) * 512))[lane];
            #pragma unroll
            for (int m = 0; m < 4; m++)
                acc[m] = __builtin_amdgcn_mfma_f32_16x16x32_f16(af[m][kt], bh, acc[m], 0, 0, 0);
        }
        #pragma unroll
        for (int m = 0; m < 4; m++)
            #pragma unroll
            for (int r = 0; r < 4; r++)
                sg[(m * 16 + quad * 4 + r) * HS + nt * 16 + lc] = f2h(silu_f(acc[m][r]));
    }
    __syncthreads();

    {
        int nt = wid;
        float bias = b2[nt * 16 + lc];
        float4v acc[4];
        #pragma unroll
        for (int m = 0; m < 4; m++) acc[m] = (float4v){bias, bias, bias, bias};
        #pragma unroll
        for (int kt = 0; kt < 4; kt++) {
            half8 bh = ((const half8*)(W2f + (size_t)(nt * 4 + kt) * 512))[lane];
            #pragma unroll
            for (int m = 0; m < 4; m++) {
                half8 a = *(const half8*)(sg + (m * 16 + lc) * HS + kt * 32 + quad * 8);
                acc[m] = __builtin_amdgcn_mfma_f32_16x16x32_f16(a, bh, acc[m], 0, 0, 0);
            }
        }
        #pragma unroll
        for (int m = 0; m < 4; m++)
            #pragma unroll
            for (int r = 0; r < 4; r++) {
                int row = m * 16 + quad * 4 + r;
                size_t idx = (size_t)(n0 + row) * FH + nt * 16 + lc;
                float nv = feats[idx] + acc[m][r];   // residual in fp32
                feats[idx] = nv;
                featsh[idx] = f2h(nv);
            }
    }
}

__global__ void final_kernel(const float* __restrict__ feats, const float* __restrict__ linW,
                             const float* __restrict__ linb, float* __restrict__ out) {
    int t = blockIdx.x * 256 + threadIdx.x;
    int n = t >> 6;
    int lane = threadIdx.x & 63;
    if (n >= NN) return;
    float v = feats[(size_t)n * FH + lane] * linW[lane];
    #pragma unroll
    for (int off = 32; off > 0; off >>= 1) v += __shfl_down(v, off);
    if (lane == 0) out[n] = v + linb[0];
}

extern "C" void kernel_launch(void* const* d_in, const int* in_sizes, int n_in,
                              void* d_out, int out_size, void* d_ws, size_t ws_size,
                              hipStream_t stream) {
    const float* x      = (const float*)d_in[0];
    const float* pos    = (const float*)d_in[1];
    const int*   ei     = (const int*)d_in[2];
    const float* eattr  = (const float*)d_in[3];
    const float* embedW = (const float*)d_in[4];
    const float* embedb = (const float*)d_in[5];
    const float* eW1    = (const float*)d_in[6];
    const float* eb1    = (const float*)d_in[7];
    const float* eW2    = (const float*)d_in[8];
    const float* eb2    = (const float*)d_in[9];
    const float* cW1    = (const float*)d_in[10];
    const float* cb1    = (const float*)d_in[11];
    const float* cW2    = (const float*)d_in[12];
    const float* cb2    = (const float*)d_in[13];
    const float* nW1    = (const float*)d_in[14];
    const float* nb1    = (const float*)d_in[15];
    const float* nW2    = (const float*)d_in[16];
    const float* nb2    = (const float*)d_in[17];
    const float* linW   = (const float*)d_in[18];
    const float* linb   = (const float*)d_in[19];
    float* out = (float*)d_out;

    char* wp = (char*)d_ws;
    auto alloc = [&](size_t bytes) { void* p = wp; wp += (bytes + 255) & ~(size_t)255; return p; };

    const int W1F_L  = 17 * 5 * 512;
    const int W2F_L  = 4 * 9 * 512;
    const int CW1F_L = 16 * 2 * 512;
    const int NW1F_L = 8 * 4 * 512;
    const int NW2F_L = 4 * 4 * 512;

    float* feats  = (float*)alloc((size_t)NNP * FH * 4);
    short* featsh = (short*)alloc((size_t)NNP * FH * 2);
    float* cA     = (float*)alloc((size_t)NN * 3 * 4);
    float* cB     = (float*)alloc((size_t)NN * 3 * 4);
    short* W1f    = (short*)alloc((size_t)3 * W1F_L * 2);
    short* W2f    = (short*)alloc((size_t)3 * W2F_L * 2);
    short* cW1f   = (short*)alloc((size_t)3 * CW1F_L * 2);
    short* nW1f   = (short*)alloc((size_t)3 * NW1F_L * 2);
    short* nW2f   = (short*)alloc((size_t)3 * NW2F_L * 2);
    float* b1p    = (float*)alloc((size_t)3 * 272 * 4);
    int*   deg    = (int*)alloc((size_t)(NN + 1) * 4);   // deg[NN] = global cursor
    int*   off    = (int*)alloc((size_t)NN * 4);
    int*   cursor = (int*)alloc((size_t)NN * 4);
    int*   erow   = (int*)alloc((size_t)NE * 4);
    int*   ecol   = (int*)alloc((size_t)NE * 4);
    float* eattrp = (float*)alloc((size_t)NE * 4);
    short* m_edge = (short*)alloc((size_t)NE * FH * 2);
    float* cwrel  = (float*)alloc((size_t)NE * 3 * 4);
    int* gcount = deg + NN;

    prep_all<<<(309552 + 255) / 256, 256, 0, stream>>>(
        eW1, eW2, cW1, nW1, nW2, eb1,
        W1f, W2f, cW1f, nW1f, nW2f, b1p);

    hipMemsetAsync(deg, 0, (size_t)(NN + 1) * 4, stream);
    hist_kernel<<<(NE + 255) / 256, 256, 0, stream>>>(ei, deg);
    alloc_kernel<<<(NN + 255) / 256, 256, 0, stream>>>(deg, off, cursor, gcount);
    fill_kernel<<<(NE + 255) / 256, 256, 0, stream>>>(ei, eattr, cursor, erow, ecol, eattrp);

    embed_kernel<<<(NN * FH + 255) / 256, 256, 0, stream>>>(x, embedW, embedb, pos, feats, featsh, cA);

    float* ccur = cA;
    float* cnext = cB;
    for (int l = 0; l < 3; l++) {
        edge_fused<<<NE / 64, 256, 0, stream>>>(
            erow, ecol, eattrp, featsh, ccur,
            W1f + (size_t)l * W1F_L, b1p + l * 272,
            W2f + (size_t)l * W2F_L, eb2 + l * 64,
            cW1f + (size_t)l * CW1F_L, cb1 + l * 256,
            cW2 + l * 256, cb2 + l,
            m_edge, cwrel);
        agg_node<<<NNP / 64, 256, 0, stream>>>(
            off, deg, m_edge, cwrel, ccur, cnext, feats, featsh,
            nW1f + (size_t)l * NW1F_L, nb1 + l * 128,
            nW2f + (size_t)l * NW2F_L, nb2 + l * 64);
        float* tmp = ccur; ccur = cnext; cnext = tmp;
    }
    final_kernel<<<(NN * FH) / 256, 256, 0, stream>>>(feats, linW, linb, out);
}